// Round 1
// baseline (1839.403 us; speedup 1.0000x reference)
//
#include <hip/hip_runtime.h>

#define NN 100000
#define RR 3
#define EE 200000
#define HH 4

// ---------------- fp32 GEMM: C[M,N] = A[M,K] @ B[K,N], optional ReLU ----------------
// BM=128, BN=64, BK=16, 256 threads, 8x4 micro-tile per thread.
__global__ __launch_bounds__(256) void gemm_f32(
    const float* __restrict__ A, const float* __restrict__ B, float* __restrict__ C,
    int M, int N, int K, int relu)
{
  __shared__ float As[16][132];   // transposed: As[k][m], pad for bank conflicts
  __shared__ float Bs[16][68];
  const int tid = threadIdx.x;
  const int ty = tid >> 4, tx = tid & 15;
  const int m0 = blockIdx.x * 128, n0 = blockIdx.y * 64;
  float acc[8][4];
  #pragma unroll
  for (int i = 0; i < 8; ++i)
    #pragma unroll
    for (int j = 0; j < 4; ++j) acc[i][j] = 0.f;

  for (int k0 = 0; k0 < K; k0 += 16) {
    // stage A tile (128 rows x 16 k), transposed into LDS
    #pragma unroll
    for (int j = 0; j < 2; ++j) {
      int idx = tid * 2 + j;          // 0..511
      int row = idx >> 2;             // 0..127
      int kc  = (idx & 3) << 2;       // 0,4,8,12
      int gm = m0 + row;
      float4 av = make_float4(0.f, 0.f, 0.f, 0.f);
      if (gm < M) av = *(const float4*)&A[(size_t)gm * K + k0 + kc];
      As[kc + 0][row] = av.x; As[kc + 1][row] = av.y;
      As[kc + 2][row] = av.z; As[kc + 3][row] = av.w;
    }
    // stage B tile (16 k x 64 n)
    {
      int row = tid >> 4;             // 0..15
      int nc  = (tid & 15) << 2;      // 0..60
      *(float4*)&Bs[row][nc] = *(const float4*)&B[(size_t)(k0 + row) * N + n0 + nc];
    }
    __syncthreads();
    #pragma unroll
    for (int kk = 0; kk < 16; ++kk) {
      float4 a0 = *(const float4*)&As[kk][ty * 8];
      float4 a1 = *(const float4*)&As[kk][ty * 8 + 4];
      float4 b0 = *(const float4*)&Bs[kk][tx * 4];
      float a[8] = {a0.x, a0.y, a0.z, a0.w, a1.x, a1.y, a1.z, a1.w};
      float b[4] = {b0.x, b0.y, b0.z, b0.w};
      #pragma unroll
      for (int i = 0; i < 8; ++i)
        #pragma unroll
        for (int j = 0; j < 4; ++j)
          acc[i][j] = fmaf(a[i], b[j], acc[i][j]);
    }
    __syncthreads();
  }
  #pragma unroll
  for (int i = 0; i < 8; ++i) {
    int gm = m0 + ty * 8 + i;
    if (gm < M) {
      float4 o = make_float4(acc[i][0], acc[i][1], acc[i][2], acc[i][3]);
      if (relu) {
        o.x = fmaxf(o.x, 0.f); o.y = fmaxf(o.y, 0.f);
        o.z = fmaxf(o.z, 0.f); o.w = fmaxf(o.w, 0.f);
      }
      *(float4*)&C[(size_t)gm * N + n0 + tx * 4] = o;
    }
  }
}

// ---------------- E1: per-edge scores -> ex, atomic denom ----------------
// wave-per-edge; lane = (head, f); score_h = sum_f (sum_d k[src,h,d]*A[r,h,d,f]) * q[dst,h,f]
template<int D, int DH>
__global__ __launch_bounds__(256) void edge_score(
    const float* __restrict__ kbuf, const float* __restrict__ qbuf,
    const int* __restrict__ EI, const float* __restrict__ A,
    const float* __restrict__ prior, float* __restrict__ exb, float* __restrict__ den)
{
  const int lane = threadIdx.x & 63;
  const int wid  = threadIdx.x >> 6;
  const int r = blockIdx.y;
  const int e = blockIdx.x * 4 + wid;
  if (e >= EE) return;
  const int src = EI[(size_t)r * 2 * EE + e];
  const int dst = EI[(size_t)r * 2 * EE + EE + e];
  const float scale = (DH == 32) ? 0.17677669529663687f : 0.25f;  // 1/sqrt(dh)
  #pragma unroll
  for (int p = 0; p < D / 64; ++p) {
    const int gf = p * 64 + lane;
    const int h = gf / DH;
    const int f = gf & (DH - 1);
    const float* __restrict__ Ah = A + (size_t)((r * HH + h) * DH) * DH;
    const float* __restrict__ kr = kbuf + (size_t)src * D + h * DH;
    float ke = 0.f;
    #pragma unroll
    for (int d = 0; d < DH; ++d)
      ke = fmaf(kr[d], Ah[d * DH + f], ke);   // kr[d]: wave-broadcast L1 hit; Ah: L1-hot
    float s = ke * qbuf[(size_t)dst * D + gf];
    #pragma unroll
    for (int off = DH / 2; off >= 1; off >>= 1)
      s += __shfl_xor(s, off, 64);            // reduce over f within head group
    if (f == 0) {
      float ex = __expf(s * prior[r * HH + h] * scale);
      exb[((size_t)r * EE + e) * HH + h] = ex;
      atomicAdd(&den[(size_t)dst * HH + h], ex);
    }
  }
}

// ---------------- E2: per-edge message * alpha -> atomic aggr ----------------
template<int D, int DH>
__global__ __launch_bounds__(256) void edge_aggr(
    const float* __restrict__ vbuf, const int* __restrict__ EI,
    const float* __restrict__ Mw, const float* __restrict__ exb,
    const float* __restrict__ den, float* __restrict__ aggr)
{
  const int lane = threadIdx.x & 63;
  const int wid  = threadIdx.x >> 6;
  const int r = blockIdx.y;
  const int e = blockIdx.x * 4 + wid;
  if (e >= EE) return;
  const int src = EI[(size_t)r * 2 * EE + e];
  const int dst = EI[(size_t)r * 2 * EE + EE + e];
  #pragma unroll
  for (int p = 0; p < D / 64; ++p) {
    const int gf = p * 64 + lane;
    const int h = gf / DH;
    const int f = gf & (DH - 1);
    const float alpha = exb[((size_t)r * EE + e) * HH + h] /
                        (den[(size_t)dst * HH + h] + 1e-9f);
    const float* __restrict__ Mh = Mw + (size_t)((r * HH + h) * DH) * DH;
    const float* __restrict__ vr = vbuf + (size_t)src * D + h * DH;
    float msg = 0.f;
    #pragma unroll
    for (int d = 0; d < DH; ++d)
      msg = fmaf(vr[d], Mh[d * DH + f], msg);
    atomicAdd(&aggr[(size_t)dst * D + gf], msg * alpha);
  }
}

extern "C" void kernel_launch(void* const* d_in, const int* in_sizes, int n_in,
                              void* d_out, int out_size, void* d_ws, size_t ws_size,
                              hipStream_t stream)
{
  const float* x   = (const float*)d_in[0];
  const int*   EI  = (const int*)  d_in[1];
  const float* Wk1 = (const float*)d_in[2];
  const float* Wq1 = (const float*)d_in[3];
  const float* Wv1 = (const float*)d_in[4];
  const float* A1  = (const float*)d_in[5];
  const float* M1  = (const float*)d_in[6];
  const float* P1  = (const float*)d_in[7];
  const float* Wo1 = (const float*)d_in[8];
  const float* Wk2 = (const float*)d_in[9];
  const float* Wq2 = (const float*)d_in[10];
  const float* Wv2 = (const float*)d_in[11];
  const float* A2  = (const float*)d_in[12];
  const float* M2  = (const float*)d_in[13];
  const float* P2  = (const float*)d_in[14];
  const float* Wo2 = (const float*)d_in[15];
  float* out = (float*)d_out;

  float* ws = (float*)d_ws;
  const size_t nd = (size_t)NN * 128;
  float* kb  = ws;                 // N*128 (layer2: N*64 reuse)
  float* qb  = ws + nd;
  float* vb  = ws + 2 * nd;
  float* ag  = ws + 3 * nd;
  float* hb  = ws + 4 * nd;        // layer-1 output (relu)
  float* exb = ws + 5 * nd;        // R*E*H
  float* den = exb + (size_t)RR * EE * HH;   // N*H
  // total ws use: (5*12.8M + 2.4M + 0.4M) floats = 267.2 MB

  dim3 blk(256);
  dim3 gg1((NN + 127) / 128, 2);   // N=128 outputs
  dim3 gg2((NN + 127) / 128, 1);   // N=64 outputs
  dim3 eg(EE / 4, RR);

  // ---------- Layer 1 (D=128, dh=32) ----------
  gemm_f32<<<gg1, blk, 0, stream>>>(x, Wk1, kb, NN, 128, 128, 0);
  gemm_f32<<<gg1, blk, 0, stream>>>(x, Wq1, qb, NN, 128, 128, 0);
  gemm_f32<<<gg1, blk, 0, stream>>>(x, Wv1, vb, NN, 128, 128, 0);
  hipMemsetAsync(den, 0, (size_t)NN * HH * sizeof(float), stream);
  edge_score<128, 32><<<eg, blk, 0, stream>>>(kb, qb, EI, A1, P1, exb, den);
  hipMemsetAsync(ag, 0, nd * sizeof(float), stream);
  edge_aggr<128, 32><<<eg, blk, 0, stream>>>(vb, EI, M1, exb, den, ag);
  gemm_f32<<<gg1, blk, 0, stream>>>(ag, Wo1, hb, NN, 128, 128, 1);  // fused ReLU

  // ---------- Layer 2 (D=64, dh=16) ----------
  gemm_f32<<<gg2, blk, 0, stream>>>(hb, Wk2, kb, NN, 64, 128, 0);
  gemm_f32<<<gg2, blk, 0, stream>>>(hb, Wq2, qb, NN, 64, 128, 0);
  gemm_f32<<<gg2, blk, 0, stream>>>(hb, Wv2, vb, NN, 64, 128, 0);
  hipMemsetAsync(den, 0, (size_t)NN * HH * sizeof(float), stream);
  edge_score<64, 16><<<eg, blk, 0, stream>>>(kb, qb, EI, A2, P2, exb, den);
  hipMemsetAsync(ag, 0, (size_t)NN * 64 * sizeof(float), stream);
  edge_aggr<64, 16><<<eg, blk, 0, stream>>>(vb, EI, M2, exb, den, ag);
  gemm_f32<<<gg2, blk, 0, stream>>>(ag, Wo2, out, NN, 64, 64, 0);
}

// Round 2
// 1557.540 us; speedup vs baseline: 1.1810x; 1.1810x over previous
//
#include <hip/hip_runtime.h>

#define NN 100000
#define RR 3
#define EE 200000
#define HH 4

// ---------------- fp32 GEMM: C[M,N] = A[M,K] @ B[K,N], optional ReLU ----------------
// BM=128, BN=64, BK=16, 256 threads, 8x4 micro-tile per thread.
__global__ __launch_bounds__(256) void gemm_f32(
    const float* __restrict__ A, const float* __restrict__ B, float* __restrict__ C,
    int M, int N, int K, int relu)
{
  __shared__ float As[16][132];   // transposed: As[k][m]
  __shared__ float Bs[16][68];
  const int tid = threadIdx.x;
  const int ty = tid >> 4, tx = tid & 15;
  const int m0 = blockIdx.x * 128, n0 = blockIdx.y * 64;
  float acc[8][4];
  #pragma unroll
  for (int i = 0; i < 8; ++i)
    #pragma unroll
    for (int j = 0; j < 4; ++j) acc[i][j] = 0.f;

  for (int k0 = 0; k0 < K; k0 += 16) {
    #pragma unroll
    for (int j = 0; j < 2; ++j) {
      int idx = tid * 2 + j;
      int row = idx >> 2;
      int kc  = (idx & 3) << 2;
      int gm = m0 + row;
      float4 av = make_float4(0.f, 0.f, 0.f, 0.f);
      if (gm < M) av = *(const float4*)&A[(size_t)gm * K + k0 + kc];
      As[kc + 0][row] = av.x; As[kc + 1][row] = av.y;
      As[kc + 2][row] = av.z; As[kc + 3][row] = av.w;
    }
    {
      int row = tid >> 4;
      int nc  = (tid & 15) << 2;
      *(float4*)&Bs[row][nc] = *(const float4*)&B[(size_t)(k0 + row) * N + n0 + nc];
    }
    __syncthreads();
    #pragma unroll
    for (int kk = 0; kk < 16; ++kk) {
      float4 a0 = *(const float4*)&As[kk][ty * 8];
      float4 a1 = *(const float4*)&As[kk][ty * 8 + 4];
      float4 b0 = *(const float4*)&Bs[kk][tx * 4];
      float a[8] = {a0.x, a0.y, a0.z, a0.w, a1.x, a1.y, a1.z, a1.w};
      float b[4] = {b0.x, b0.y, b0.z, b0.w};
      #pragma unroll
      for (int i = 0; i < 8; ++i)
        #pragma unroll
        for (int j = 0; j < 4; ++j)
          acc[i][j] = fmaf(a[i], b[j], acc[i][j]);
    }
    __syncthreads();
  }
  #pragma unroll
  for (int i = 0; i < 8; ++i) {
    int gm = m0 + ty * 8 + i;
    if (gm < M) {
      float4 o = make_float4(acc[i][0], acc[i][1], acc[i][2], acc[i][3]);
      if (relu) {
        o.x = fmaxf(o.x, 0.f); o.y = fmaxf(o.y, 0.f);
        o.z = fmaxf(o.z, 0.f); o.w = fmaxf(o.w, 0.f);
      }
      *(float4*)&C[(size_t)gm * N + n0 + tx * 4] = o;
    }
  }
}

// ---------------- weight-space fusion: out[i][r*D + h*dh + f] = sum_d W[i][h*dh+d]*T[r][h][d][f]
__global__ __launch_bounds__(256) void build_w(
    const float* __restrict__ W, const float* __restrict__ T,
    float* __restrict__ out, int F, int D, int dh)
{
  const int cols = RR * D;
  int idx = blockIdx.x * 256 + threadIdx.x;
  if (idx >= F * cols) return;
  int i = idx / cols, c = idx % cols;
  int r = c / D, gf = c % D;
  int h = gf / dh, f = gf % dh;
  const float* w = W + (size_t)i * D + h * dh;
  const float* t = T + ((size_t)(r * HH + h) * dh) * dh + f;
  float s = 0.f;
  for (int d = 0; d < dh; ++d) s = fmaf(w[d], t[(size_t)d * dh], s);
  out[(size_t)i * cols + c] = s;
}

// ---------------- E1: per-edge score = dot(kA[src], q[dst]) per head -> ex, atomic denom
template<int D, int DH>
__global__ __launch_bounds__(256) void edge_score(
    const float* __restrict__ kA,   // N x (R*D), relation-strided
    const float* __restrict__ q,    // N x D
    const int* __restrict__ EI, const float* __restrict__ prior,
    float* __restrict__ exb, float* __restrict__ den)
{
  constexpr int LPE = D / 2;      // lanes per edge (float2 each)
  constexpr int EPW = 64 / LPE;   // edges per wave
  constexpr int SUB = DH / 2;     // lanes per head
  const int lane = threadIdx.x & 63;
  const int wv = blockIdx.x * 4 + (threadIdx.x >> 6);
  const int r = blockIdx.y;
  const int e = wv * EPW + lane / LPE;
  const int sl = lane % LPE;
  if (e >= EE) return;
  const int src = EI[(size_t)r * 2 * EE + e];
  const int dst = EI[(size_t)r * 2 * EE + EE + e];
  const float2 ka = *(const float2*)&kA[(size_t)src * (RR * D) + r * D + sl * 2];
  const float2 qq = *(const float2*)&q[(size_t)dst * D + sl * 2];
  float s = ka.x * qq.x + ka.y * qq.y;
  #pragma unroll
  for (int off = SUB / 2; off >= 1; off >>= 1) s += __shfl_xor(s, off, 64);
  if (sl % SUB == 0) {
    const int h = sl / SUB;
    constexpr float scale = (DH == 32) ? 0.17677669529663687f : 0.25f;
    float ex = __expf(s * prior[r * HH + h] * scale);
    exb[((size_t)r * EE + e) * HH + h] = ex;
    atomicAdd(&den[(size_t)dst * HH + h], ex);
  }
}

// ---------------- E2: per-edge msg = vM[src] * alpha -> atomic aggr
template<int D, int DH>
__global__ __launch_bounds__(256) void edge_aggr(
    const float* __restrict__ vM,   // N x (R*D)
    const int* __restrict__ EI,
    const float* __restrict__ exb, const float* __restrict__ den,
    float* __restrict__ ag)
{
  constexpr int LPE = D / 2;
  constexpr int EPW = 64 / LPE;
  constexpr int SUB = DH / 2;
  const int lane = threadIdx.x & 63;
  const int wv = blockIdx.x * 4 + (threadIdx.x >> 6);
  const int r = blockIdx.y;
  const int e = wv * EPW + lane / LPE;
  const int sl = lane % LPE;
  if (e >= EE) return;
  const int src = EI[(size_t)r * 2 * EE + e];
  const int dst = EI[(size_t)r * 2 * EE + EE + e];
  const int h = sl / SUB;
  const float al = exb[((size_t)r * EE + e) * HH + h] /
                   (den[(size_t)dst * HH + h] + 1e-9f);
  const float2 vm = *(const float2*)&vM[(size_t)src * (RR * D) + r * D + sl * 2];
  atomicAdd(&ag[(size_t)dst * D + sl * 2],     vm.x * al);
  atomicAdd(&ag[(size_t)dst * D + sl * 2 + 1], vm.y * al);
}

extern "C" void kernel_launch(void* const* d_in, const int* in_sizes, int n_in,
                              void* d_out, int out_size, void* d_ws, size_t ws_size,
                              hipStream_t stream)
{
  const float* x   = (const float*)d_in[0];
  const int*   EI  = (const int*)  d_in[1];
  const float* Wk1 = (const float*)d_in[2];
  const float* Wq1 = (const float*)d_in[3];
  const float* Wv1 = (const float*)d_in[4];
  const float* A1  = (const float*)d_in[5];
  const float* M1  = (const float*)d_in[6];
  const float* P1  = (const float*)d_in[7];
  const float* Wo1 = (const float*)d_in[8];
  const float* Wk2 = (const float*)d_in[9];
  const float* Wq2 = (const float*)d_in[10];
  const float* Wv2 = (const float*)d_in[11];
  const float* A2  = (const float*)d_in[12];
  const float* M2  = (const float*)d_in[13];
  const float* P2  = (const float*)d_in[14];
  const float* Wo2 = (const float*)d_in[15];
  float* out = (float*)d_out;

  float* ws = (float*)d_ws;
  const size_t nd = (size_t)NN * 128;
  float* P   = ws;                          // 3*nd : kA / vM (N x R*D)
  float* Q   = ws + 3 * nd;                 // nd   : q, then aggr
  float* Hb  = ws + 4 * nd;                 // nd   : layer-1 output
  float* exb = ws + 5 * nd;                 // R*E*H
  float* den = exb + (size_t)RR * EE * HH;  // N*H
  float* WB  = den + (size_t)NN * HH;       // 128*384 fused-weight scratch
  // total: 5*nd + 2.4M + 0.4M + 49K floats = 267.4 MB (same footprint as round 1)

  dim3 blk(256);

  // ---------- Layer 1 (D=128, dh=32) ----------
  gemm_f32<<<dim3(782, 2), blk, 0, stream>>>(x, Wq1, Q, NN, 128, 128, 0);
  build_w<<<dim3(192), blk, 0, stream>>>(Wk1, A1, WB, 128, 128, 32);
  gemm_f32<<<dim3(782, 6), blk, 0, stream>>>(x, WB, P, NN, 384, 128, 0);
  hipMemsetAsync(den, 0, (size_t)NN * HH * sizeof(float), stream);
  edge_score<128, 32><<<dim3(50000, 3), blk, 0, stream>>>(P, Q, EI, P1, exb, den);
  build_w<<<dim3(192), blk, 0, stream>>>(Wv1, M1, WB, 128, 128, 32);
  gemm_f32<<<dim3(782, 6), blk, 0, stream>>>(x, WB, P, NN, 384, 128, 0);
  hipMemsetAsync(Q, 0, nd * sizeof(float), stream);
  edge_aggr<128, 32><<<dim3(50000, 3), blk, 0, stream>>>(P, EI, exb, den, Q);
  gemm_f32<<<dim3(782, 2), blk, 0, stream>>>(Q, Wo1, Hb, NN, 128, 128, 1);

  // ---------- Layer 2 (D=64, dh=16) ----------
  gemm_f32<<<dim3(782, 1), blk, 0, stream>>>(Hb, Wq2, Q, NN, 64, 128, 0);
  build_w<<<dim3(96), blk, 0, stream>>>(Wk2, A2, WB, 128, 64, 16);
  gemm_f32<<<dim3(782, 3), blk, 0, stream>>>(Hb, WB, P, NN, 192, 128, 0);
  hipMemsetAsync(den, 0, (size_t)NN * HH * sizeof(float), stream);
  edge_score<64, 16><<<dim3(25000, 3), blk, 0, stream>>>(P, Q, EI, P2, exb, den);
  build_w<<<dim3(96), blk, 0, stream>>>(Wv2, M2, WB, 128, 64, 16);
  gemm_f32<<<dim3(782, 3), blk, 0, stream>>>(Hb, WB, P, NN, 192, 128, 0);
  float* ag2 = Q + nd / 2;
  hipMemsetAsync(ag2, 0, (nd / 2) * sizeof(float), stream);
  edge_aggr<64, 16><<<dim3(25000, 3), blk, 0, stream>>>(P, EI, exb, den, ag2);
  gemm_f32<<<dim3(782, 1), blk, 0, stream>>>(ag2, Wo2, out, NN, 64, 64, 0);
}

// Round 6
// 984.455 us; speedup vs baseline: 1.8684x; 1.5821x over previous
//
#include <hip/hip_runtime.h>

#define NN 100000
#define RR 3
#define EE 200000
#define HH 4
#define ETOT (RR * EE)
#define NB ((NN + 255) / 256)

__device__ __forceinline__ int clampi(int v, int lo, int hi) {
  return v < lo ? lo : (v > hi ? hi : v);
}

// ---------------- fp32 GEMM: C[M,N] = A[M,K] @ B[K,N], optional ReLU ----------------
__global__ __launch_bounds__(256) void gemm_f32(
    const float* __restrict__ A, const float* __restrict__ B, float* __restrict__ C,
    int M, int N, int K, int relu)
{
  __shared__ float As[16][132];
  __shared__ float Bs[16][68];
  const int tid = threadIdx.x;
  const int ty = tid >> 4, tx = tid & 15;
  const int m0 = blockIdx.x * 128, n0 = blockIdx.y * 64;
  float acc[8][4];
  #pragma unroll
  for (int i = 0; i < 8; ++i)
    #pragma unroll
    for (int j = 0; j < 4; ++j) acc[i][j] = 0.f;

  for (int k0 = 0; k0 < K; k0 += 16) {
    #pragma unroll
    for (int j = 0; j < 2; ++j) {
      int idx = tid * 2 + j;
      int row = idx >> 2;
      int kc  = (idx & 3) << 2;
      int gm = m0 + row;
      float4 av = make_float4(0.f, 0.f, 0.f, 0.f);
      if (gm < M) av = *(const float4*)&A[(size_t)gm * K + k0 + kc];
      As[kc + 0][row] = av.x; As[kc + 1][row] = av.y;
      As[kc + 2][row] = av.z; As[kc + 3][row] = av.w;
    }
    {
      int row = tid >> 4;
      int nc  = (tid & 15) << 2;
      *(float4*)&Bs[row][nc] = *(const float4*)&B[(size_t)(k0 + row) * N + n0 + nc];
    }
    __syncthreads();
    #pragma unroll
    for (int kk = 0; kk < 16; ++kk) {
      float4 a0 = *(const float4*)&As[kk][ty * 8];
      float4 a1 = *(const float4*)&As[kk][ty * 8 + 4];
      float4 b0 = *(const float4*)&Bs[kk][tx * 4];
      float a[8] = {a0.x, a0.y, a0.z, a0.w, a1.x, a1.y, a1.z, a1.w};
      float b[4] = {b0.x, b0.y, b0.z, b0.w};
      #pragma unroll
      for (int i = 0; i < 8; ++i)
        #pragma unroll
        for (int j = 0; j < 4; ++j)
          acc[i][j] = fmaf(a[i], b[j], acc[i][j]);
    }
    __syncthreads();
  }
  #pragma unroll
  for (int i = 0; i < 8; ++i) {
    int gm = m0 + ty * 8 + i;
    if (gm < M) {
      float4 o = make_float4(acc[i][0], acc[i][1], acc[i][2], acc[i][3]);
      if (relu) {
        o.x = fmaxf(o.x, 0.f); o.y = fmaxf(o.y, 0.f);
        o.z = fmaxf(o.z, 0.f); o.w = fmaxf(o.w, 0.f);
      }
      *(float4*)&C[(size_t)gm * N + n0 + tx * 4] = o;
    }
  }
}

// ---------------- weight-space fusion ----------------
__global__ __launch_bounds__(256) void build_w(
    const float* __restrict__ W, const float* __restrict__ T,
    float* __restrict__ out, int F, int D, int dh)
{
  const int cols = RR * D;
  int idx = blockIdx.x * 256 + threadIdx.x;
  if (idx >= F * cols) return;
  int i = idx / cols, c = idx % cols;
  int r = c / D, gf = c % D;
  int h = gf / dh, f = gf % dh;
  const float* w = W + (size_t)i * D + h * dh;
  const float* t = T + ((size_t)(r * HH + h) * dh) * dh + f;
  float s = 0.f;
  for (int d = 0; d < dh; ++d) s = fmaf(w[d], t[(size_t)d * dh], s);
  out[(size_t)i * cols + c] = s;
}

// ---------------- CSR build ----------------
__global__ __launch_bounds__(256) void zero_i32(int* __restrict__ p, int n)
{
  int i = blockIdx.x * 256 + threadIdx.x;
  if (i < n) p[i] = 0;
}

__global__ __launch_bounds__(256) void csr_count(
    const int* __restrict__ EI, int* __restrict__ cnt)
{
  int idx = blockIdx.x * 256 + threadIdx.x;
  if (idx >= ETOT) return;
  int r = idx / EE, e = idx % EE;
  int dst = clampi(EI[(size_t)r * 2 * EE + EE + e], 0, NN - 1);
  atomicAdd(&cnt[dst], 1);
}

__global__ __launch_bounds__(256) void scan_intra(
    int* __restrict__ arr, int* __restrict__ blksum)
{
  __shared__ int s[256];
  const int t = threadIdx.x;
  const int i = blockIdx.x * 256 + t;
  int v = (i < NN) ? arr[i] : 0;
  s[t] = v;
  __syncthreads();
  #pragma unroll
  for (int off = 1; off < 256; off <<= 1) {
    int x = (t >= off) ? s[t - off] : 0;
    __syncthreads();
    s[t] += x;
    __syncthreads();
  }
  if (i < NN) arr[i] = s[t] - v;        // exclusive
  if (t == 255) blksum[blockIdx.x] = s[255];
}

// single-block scan of NB block-sums, chunked with explicit carry
__global__ __launch_bounds__(256) void scan_mid(
    const int* __restrict__ blksum, int* __restrict__ blkoff)
{
  __shared__ int s[256];
  __shared__ int carry;
  const int t = threadIdx.x;
  if (t == 0) carry = 0;
  __syncthreads();
  for (int base = 0; base < NB; base += 256) {
    const int i = base + t;
    int v = (i < NB) ? blksum[i] : 0;
    s[t] = v;
    __syncthreads();
    #pragma unroll
    for (int off = 1; off < 256; off <<= 1) {
      int x = (t >= off) ? s[t - off] : 0;
      __syncthreads();
      s[t] += x;
      __syncthreads();
    }
    if (i < NB) blkoff[i] = carry + s[t] - v;   // global exclusive
    __syncthreads();
    if (t == 255) carry += s[255];
    __syncthreads();
  }
}

__global__ __launch_bounds__(256) void scan_add(
    int* __restrict__ arr, const int* __restrict__ blkoff,
    int* __restrict__ rowptr, int* __restrict__ cursor)
{
  int i = blockIdx.x * 256 + threadIdx.x;
  if (i < NN) {
    int v = arr[i] + blkoff[i >> 8];
    rowptr[i] = v;
    cursor[i] = v;
  }
  if (i == NN) rowptr[NN] = ETOT;
}

__global__ __launch_bounds__(256) void csr_scatter(
    const int* __restrict__ EI, int* __restrict__ cursor,
    int* __restrict__ srcrel, int* __restrict__ dstA)
{
  int idx = blockIdx.x * 256 + threadIdx.x;
  if (idx >= ETOT) return;
  int r = idx / EE, e = idx % EE;
  int src = clampi(EI[(size_t)r * 2 * EE + e], 0, NN - 1);
  int dst = clampi(EI[(size_t)r * 2 * EE + EE + e], 0, NN - 1);
  int pos = atomicAdd(&cursor[dst], 1);
  pos = clampi(pos, 0, ETOT - 1);            // fault-proof scatter
  srcrel[pos] = src | (r << 24);
  dstA[pos]   = dst;
}

// ---------------- E1: per-sorted-edge score -> ex (no atomics) ----------------
template<int D, int DH>
__global__ __launch_bounds__(256) void edge_score(
    const float* __restrict__ kA, const float* __restrict__ q,
    const int* __restrict__ srcrel, const int* __restrict__ dstA,
    const float* __restrict__ prior, float* __restrict__ exb)
{
  constexpr int LPE = D / 2;
  constexpr int EPW = 64 / LPE;
  constexpr int SUB = DH / 2;
  const int lane = threadIdx.x & 63;
  const int wv = blockIdx.x * 4 + (threadIdx.x >> 6);
  const int j = wv * EPW + lane / LPE;
  const int sl = lane % LPE;
  if (j >= ETOT) return;
  const int word = srcrel[j];
  const int src = clampi(word & 0xFFFFFF, 0, NN - 1);
  const int r = clampi(word >> 24, 0, RR - 1);
  const int dst = clampi(dstA[j], 0, NN - 1);
  const float2 ka = *(const float2*)&kA[(size_t)src * (RR * D) + r * D + sl * 2];
  const float2 qq = *(const float2*)&q[(size_t)dst * D + sl * 2];
  float s = ka.x * qq.x + ka.y * qq.y;
  #pragma unroll
  for (int off = SUB / 2; off >= 1; off >>= 1) s += __shfl_xor(s, off, 64);
  if (sl % SUB == 0) {
    const int h = sl / SUB;
    constexpr float scale = (DH == 32) ? 0.17677669529663687f : 0.25f;
    exb[(size_t)j * HH + h] = __expf(s * prior[r * HH + h] * scale);
  }
}

// ---------------- E2: per-node gather aggregation ----------------
template<int D, int DH>
__global__ __launch_bounds__(256) void node_aggr(
    const float* __restrict__ vM, const int* __restrict__ rowptr,
    const int* __restrict__ srcrel, const float* __restrict__ exb,
    float* __restrict__ ag)
{
  const int lane = threadIdx.x & 63;
  const int n = blockIdx.x * 4 + (threadIdx.x >> 6);
  if (n >= NN) return;
  int j0 = clampi(rowptr[n], 0, ETOT);
  int j1 = clampi(rowptr[n + 1], j0, ETOT);
  if (D == 128) {
    const int h = lane >> 4;
    float2 acc = make_float2(0.f, 0.f);
    float den = 0.f;
    for (int j = j0; j < j1; ++j) {
      const int word = srcrel[j];
      const int src = clampi(word & 0xFFFFFF, 0, NN - 1);
      const int r = clampi(word >> 24, 0, RR - 1);
      const float ex = exb[(size_t)j * HH + h];
      const float2 vm = *(const float2*)&vM[(size_t)src * (RR * D) + r * D + lane * 2];
      den += ex;
      acc.x = fmaf(ex, vm.x, acc.x);
      acc.y = fmaf(ex, vm.y, acc.y);
    }
    const float inv = 1.f / (den + 1e-9f);
    *(float2*)&ag[(size_t)n * D + lane * 2] = make_float2(acc.x * inv, acc.y * inv);
  } else {
    const int h = lane >> 4;
    float acc = 0.f;
    float den = 0.f;
    for (int j = j0; j < j1; ++j) {
      const int word = srcrel[j];
      const int src = clampi(word & 0xFFFFFF, 0, NN - 1);
      const int r = clampi(word >> 24, 0, RR - 1);
      const float ex = exb[(size_t)j * HH + h];
      den += ex;
      acc = fmaf(ex, vM[(size_t)src * (RR * D) + r * D + lane], acc);
    }
    ag[(size_t)n * D + lane] = acc / (den + 1e-9f);
  }
}

extern "C" void kernel_launch(void* const* d_in, const int* in_sizes, int n_in,
                              void* d_out, int out_size, void* d_ws, size_t ws_size,
                              hipStream_t stream)
{
  const float* x   = (const float*)d_in[0];
  const int*   EI  = (const int*)  d_in[1];
  const float* Wk1 = (const float*)d_in[2];
  const float* Wq1 = (const float*)d_in[3];
  const float* Wv1 = (const float*)d_in[4];
  const float* A1  = (const float*)d_in[5];
  const float* M1  = (const float*)d_in[6];
  const float* P1  = (const float*)d_in[7];
  const float* Wo1 = (const float*)d_in[8];
  const float* Wk2 = (const float*)d_in[9];
  const float* Wq2 = (const float*)d_in[10];
  const float* Wv2 = (const float*)d_in[11];
  const float* A2  = (const float*)d_in[12];
  const float* M2  = (const float*)d_in[13];
  const float* P2  = (const float*)d_in[14];
  const float* Wo2 = (const float*)d_in[15];
  float* out = (float*)d_out;

  float* ws = (float*)d_ws;
  const size_t nd = (size_t)NN * 128;
  float* P  = ws;                  // 3*nd : kA / vM  (layer2: kA2 | vM2 halves)
  float* Q  = ws + 3 * nd;         // nd   : q, then ag
  float* Hb = ws + 4 * nd;         // nd   : layer-1 output; exb aliases while Hb dead
  float* WB = ws + 5 * nd;         // 128*384 floats (16B-aligned)
  int* ints   = (int*)(WB + 49152);
  int* rowptr = ints;              // NN+1
  int* cursor = rowptr + NN + 1;   // NN
  int* blks   = cursor + NN;       // 2*NB
  int* srcrel = blks + 2 * NB;     // ETOT
  int* dstA   = srcrel + ETOT;     // ETOT
  float* exb  = Hb;                // ETOT*HH floats inside Hb while Hb dead

  const size_t need_bytes = (5 * nd + 49152) * 4 +
      ((size_t)(NN + 1) + NN + 2 * NB + 2 * ETOT) * 4;
  if (ws_size < need_bytes) return;   // visible absmax failure, not a fault

  dim3 blk(256);

  // ---------- Layer 1 (D=128, dh=32); first captured node is a GEMM ----------
  gemm_f32<<<dim3(782, 2), blk, 0, stream>>>(x, Wq1, Q, NN, 128, 128, 0);

  zero_i32<<<dim3(NB), blk, 0, stream>>>(cursor, NN);
  csr_count<<<dim3((ETOT + 255) / 256), blk, 0, stream>>>(EI, cursor);
  scan_intra<<<dim3(NB), blk, 0, stream>>>(cursor, blks);
  scan_mid<<<dim3(1), blk, 0, stream>>>(blks, blks + NB);
  scan_add<<<dim3(NB), blk, 0, stream>>>(cursor, blks + NB, rowptr, cursor);
  csr_scatter<<<dim3((ETOT + 255) / 256), blk, 0, stream>>>(EI, cursor, srcrel, dstA);

  build_w<<<dim3(192), blk, 0, stream>>>(Wk1, A1, WB, 128, 128, 32);
  gemm_f32<<<dim3(782, 6), blk, 0, stream>>>(x, WB, P, NN, 384, 128, 0);
  edge_score<128, 32><<<dim3((ETOT + 3) / 4), blk, 0, stream>>>(P, Q, srcrel, dstA, P1, exb);
  build_w<<<dim3(192), blk, 0, stream>>>(Wv1, M1, WB, 128, 128, 32);
  gemm_f32<<<dim3(782, 6), blk, 0, stream>>>(x, WB, P, NN, 384, 128, 0);
  node_aggr<128, 32><<<dim3((NN + 3) / 4), blk, 0, stream>>>(P, rowptr, srcrel, exb, Q);
  gemm_f32<<<dim3(782, 2), blk, 0, stream>>>(Q, Wo1, Hb, NN, 128, 128, 1);  // overwrites exb (dead)

  // ---------- Layer 2 (D=64, dh=16): all Hb readers before exb overwrites Hb ----------
  build_w<<<dim3(96), blk, 0, stream>>>(Wk2, A2, WB, 128, 64, 16);
  gemm_f32<<<dim3(782, 3), blk, 0, stream>>>(Hb, WB, P, NN, 192, 128, 0);            // kA2
  build_w<<<dim3(96), blk, 0, stream>>>(Wv2, M2, WB, 128, 64, 16);
  gemm_f32<<<dim3(782, 3), blk, 0, stream>>>(Hb, WB, P + (size_t)NN * 192, NN, 192, 128, 0); // vM2
  gemm_f32<<<dim3(782, 1), blk, 0, stream>>>(Hb, Wq2, Q, NN, 64, 128, 0);            // q2
  edge_score<64, 16><<<dim3((ETOT + 7) / 8), blk, 0, stream>>>(P, Q, srcrel, dstA, P2, exb);
  float* ag2 = Q + nd / 2;
  node_aggr<64, 16><<<dim3((NN + 3) / 4), blk, 0, stream>>>(P + (size_t)NN * 192, rowptr, srcrel, exb, ag2);
  gemm_f32<<<dim3(782, 1), blk, 0, stream>>>(ag2, Wo2, out, NN, 64, 64, 0);
}

// Round 8
// 753.837 us; speedup vs baseline: 2.4401x; 1.3059x over previous
//
#include <hip/hip_runtime.h>

#define NN 100000
#define RR 3
#define EE 200000
#define HH 4
#define ETOT (RR * EE)
#define NB ((NN + 255) / 256)

typedef __attribute__((ext_vector_type(8))) short bf16x8;
typedef __attribute__((ext_vector_type(4))) float f32x4;

__device__ __forceinline__ int clampi(int v, int lo, int hi) {
  return v < lo ? lo : (v > hi ? hi : v);
}

// split fp32 -> bf16 hi + bf16 lo (RNE both): a ~= hi + lo, residual ~2^-18
__device__ __forceinline__ void split2(float v, ushort& h, ushort& l) {
  uint u = __float_as_uint(v);
  uint hb = (u + 0x7FFFu + ((u >> 16) & 1u)) >> 16;
  float fh = __uint_as_float(hb << 16);
  float r = v - fh;
  uint ur = __float_as_uint(r);
  uint lb = (ur + 0x7FFFu + ((ur >> 16) & 1u)) >> 16;
  h = (ushort)hb; l = (ushort)lb;
}

// ---------------- split-bf16 MFMA GEMM: C[M,N] = A[M,K] @ B[K,N] ----------------
// A fp32 row-major (split in-kernel). B pre-split+transposed: Bth/Btl = [N][K] bf16.
// Tile 128x64, 256 thr = 4 waves, wave = 32 rows x 64 cols (2x4 16x16 frags).
// 3 MFMAs per product term: hi*hi + hi*lo + lo*hi (lo*lo dropped, ~2^-18).
__global__ __launch_bounds__(256) void gemm_sbf(
    const float* __restrict__ A, const ushort* __restrict__ Bth,
    const ushort* __restrict__ Btl, float* __restrict__ C,
    int M, int N, int K, int relu)
{
  __shared__ uint Bh[64 * 68];   // [col][K shorts padded to 136] as dwords (68/row)
  __shared__ uint Bl[64 * 68];
  const int tid = threadIdx.x;
  const int m0 = blockIdx.x * 128, n0 = blockIdx.y * 64;

  // stage B hi/lo tile: thread t covers col c = t>>2, k-quarter kq = t&3
  // (32 shorts = 64 B = FOUR uint4 each; round-7 bug: only 2 copied -> NaN)
  {
    const int c = tid >> 2, kq = tid & 3;
    if (kq * 32 < K) {
      const uint4* sh = (const uint4*)(Bth + (size_t)(n0 + c) * K + kq * 32);
      const uint4* sl = (const uint4*)(Btl + (size_t)(n0 + c) * K + kq * 32);
      uint4* dh = (uint4*)&Bh[c * 68 + kq * 16];
      uint4* dl = (uint4*)&Bl[c * 68 + kq * 16];
      #pragma unroll
      for (int q = 0; q < 4; ++q) { dh[q] = sh[q]; dl[q] = sl[q]; }
    }
  }
  __syncthreads();

  const int lane = tid & 63, wv = tid >> 6;
  const int rbase = m0 + wv * 32 + (lane & 15);
  const int kof = (lane >> 4) * 8;

  f32x4 acc[2][4];
  #pragma unroll
  for (int m = 0; m < 2; ++m)
    #pragma unroll
    for (int n = 0; n < 4; ++n) acc[m][n] = (f32x4){0.f, 0.f, 0.f, 0.f};

  for (int kk = 0; kk < K; kk += 32) {
    const int kt = kk >> 5;
    bf16x8 ah[2], al[2];
    #pragma unroll
    for (int m = 0; m < 2; ++m) {
      const int row = rbase + m * 16;
      float4 a0 = make_float4(0.f, 0.f, 0.f, 0.f);
      float4 a1 = make_float4(0.f, 0.f, 0.f, 0.f);
      if (row < M) {
        const float4* ap = (const float4*)(A + (size_t)row * K + kk + kof);
        a0 = ap[0]; a1 = ap[1];
      }
      const float v[8] = {a0.x, a0.y, a0.z, a0.w, a1.x, a1.y, a1.z, a1.w};
      #pragma unroll
      for (int i = 0; i < 8; ++i) {
        ushort h, l; split2(v[i], h, l);
        ah[m][i] = (short)h; al[m][i] = (short)l;
      }
    }
    #pragma unroll
    for (int n = 0; n < 4; ++n) {
      const int boff = (n * 16 + (lane & 15)) * 68 + kt * 16 + (lane >> 4) * 4;
      uint4 uh = *(const uint4*)&Bh[boff];
      uint4 ul = *(const uint4*)&Bl[boff];
      bf16x8 bh = *reinterpret_cast<bf16x8*>(&uh);
      bf16x8 bl = *reinterpret_cast<bf16x8*>(&ul);
      #pragma unroll
      for (int m = 0; m < 2; ++m) {
        acc[m][n] = __builtin_amdgcn_mfma_f32_16x16x32_bf16(ah[m], bh, acc[m][n], 0, 0, 0);
        acc[m][n] = __builtin_amdgcn_mfma_f32_16x16x32_bf16(ah[m], bl, acc[m][n], 0, 0, 0);
        acc[m][n] = __builtin_amdgcn_mfma_f32_16x16x32_bf16(al[m], bh, acc[m][n], 0, 0, 0);
      }
    }
  }

  // C/D frag mapping (m89-verified): col = lane&15, row = (lane>>4)*4 + j
  #pragma unroll
  for (int m = 0; m < 2; ++m) {
    const int rw = m0 + wv * 32 + m * 16 + (lane >> 4) * 4;
    #pragma unroll
    for (int n = 0; n < 4; ++n) {
      const int col = n0 + n * 16 + (lane & 15);
      #pragma unroll
      for (int j = 0; j < 4; ++j) {
        if (rw + j < M) {
          float o = acc[m][n][j];
          if (relu) o = fmaxf(o, 0.f);
          C[(size_t)(rw + j) * N + col] = o;
        }
      }
    }
  }
}

// ---------------- plain weight -> transposed split-bf16: W[K][N] -> T[N][K] hi/lo ----
__global__ __launch_bounds__(256) void convt(
    const float* __restrict__ W, ushort* __restrict__ Th, ushort* __restrict__ Tl,
    int K, int N)
{
  int idx = blockIdx.x * 256 + threadIdx.x;
  if (idx >= K * N) return;
  int n = idx / K, k = idx % K;
  ushort h, l; split2(W[(size_t)k * N + n], h, l);
  Th[(size_t)n * K + k] = h;
  Tl[(size_t)n * K + k] = l;
}

// ---------------- weight-space fusion -> transposed split-bf16 ----------------
__global__ __launch_bounds__(256) void build_wT(
    const float* __restrict__ W, const float* __restrict__ T,
    ushort* __restrict__ Oh, ushort* __restrict__ Ol, int F, int D, int dh)
{
  const int cols = RR * D;
  int idx = blockIdx.x * 256 + threadIdx.x;
  if (idx >= F * cols) return;
  int i = idx / cols, c = idx % cols;
  int r = c / D, gf = c % D;
  int h = gf / dh, f = gf % dh;
  const float* w = W + (size_t)i * D + h * dh;
  const float* t = T + ((size_t)(r * HH + h) * dh) * dh + f;
  float s = 0.f;
  for (int d = 0; d < dh; ++d) s = fmaf(w[d], t[(size_t)d * dh], s);
  ushort hh, ll; split2(s, hh, ll);
  Oh[(size_t)c * F + i] = hh;
  Ol[(size_t)c * F + i] = ll;
}

// ---------------- CSR build ----------------
__global__ __launch_bounds__(256) void zero_i32(int* __restrict__ p, int n)
{
  int i = blockIdx.x * 256 + threadIdx.x;
  if (i < n) p[i] = 0;
}

__global__ __launch_bounds__(256) void csr_count(
    const int* __restrict__ EI, int* __restrict__ cnt)
{
  int idx = blockIdx.x * 256 + threadIdx.x;
  if (idx >= ETOT) return;
  int r = idx / EE, e = idx % EE;
  int dst = clampi(EI[(size_t)r * 2 * EE + EE + e], 0, NN - 1);
  atomicAdd(&cnt[dst], 1);
}

__global__ __launch_bounds__(256) void scan_intra(
    int* __restrict__ arr, int* __restrict__ blksum)
{
  __shared__ int s[256];
  const int t = threadIdx.x;
  const int i = blockIdx.x * 256 + t;
  int v = (i < NN) ? arr[i] : 0;
  s[t] = v;
  __syncthreads();
  #pragma unroll
  for (int off = 1; off < 256; off <<= 1) {
    int x = (t >= off) ? s[t - off] : 0;
    __syncthreads();
    s[t] += x;
    __syncthreads();
  }
  if (i < NN) arr[i] = s[t] - v;        // exclusive
  if (t == 255) blksum[blockIdx.x] = s[255];
}

__global__ __launch_bounds__(256) void scan_mid(
    const int* __restrict__ blksum, int* __restrict__ blkoff)
{
  __shared__ int s[256];
  __shared__ int carry;
  const int t = threadIdx.x;
  if (t == 0) carry = 0;
  __syncthreads();
  for (int base = 0; base < NB; base += 256) {
    const int i = base + t;
    int v = (i < NB) ? blksum[i] : 0;
    s[t] = v;
    __syncthreads();
    #pragma unroll
    for (int off = 1; off < 256; off <<= 1) {
      int x = (t >= off) ? s[t - off] : 0;
      __syncthreads();
      s[t] += x;
      __syncthreads();
    }
    if (i < NB) blkoff[i] = carry + s[t] - v;   // global exclusive
    __syncthreads();
    if (t == 255) carry += s[255];
    __syncthreads();
  }
}

__global__ __launch_bounds__(256) void scan_add(
    int* __restrict__ arr, const int* __restrict__ blkoff,
    int* __restrict__ rowptr, int* __restrict__ cursor)
{
  int i = blockIdx.x * 256 + threadIdx.x;
  if (i < NN) {
    int v = arr[i] + blkoff[i >> 8];
    rowptr[i] = v;
    cursor[i] = v;
  }
  if (i == NN) rowptr[NN] = ETOT;
}

__global__ __launch_bounds__(256) void csr_scatter(
    const int* __restrict__ EI, int* __restrict__ cursor,
    int* __restrict__ srcrel, int* __restrict__ dstA)
{
  int idx = blockIdx.x * 256 + threadIdx.x;
  if (idx >= ETOT) return;
  int r = idx / EE, e = idx % EE;
  int src = clampi(EI[(size_t)r * 2 * EE + e], 0, NN - 1);
  int dst = clampi(EI[(size_t)r * 2 * EE + EE + e], 0, NN - 1);
  int pos = atomicAdd(&cursor[dst], 1);
  pos = clampi(pos, 0, ETOT - 1);
  srcrel[pos] = src | (r << 24);
  dstA[pos]   = dst;
}

// ---------------- E1: per-sorted-edge score -> ex (no atomics) ----------------
template<int D, int DH>
__global__ __launch_bounds__(256) void edge_score(
    const float* __restrict__ kA, const float* __restrict__ q,
    const int* __restrict__ srcrel, const int* __restrict__ dstA,
    const float* __restrict__ prior, float* __restrict__ exb)
{
  constexpr int LPE = D / 2;
  constexpr int EPW = 64 / LPE;
  constexpr int SUB = DH / 2;
  const int lane = threadIdx.x & 63;
  const int wv = blockIdx.x * 4 + (threadIdx.x >> 6);
  const int j = wv * EPW + lane / LPE;
  const int sl = lane % LPE;
  if (j >= ETOT) return;
  const int word = srcrel[j];
  const int src = clampi(word & 0xFFFFFF, 0, NN - 1);
  const int r = clampi(word >> 24, 0, RR - 1);
  const int dst = clampi(dstA[j], 0, NN - 1);
  const float2 ka = *(const float2*)&kA[(size_t)src * (RR * D) + r * D + sl * 2];
  const float2 qq = *(const float2*)&q[(size_t)dst * D + sl * 2];
  float s = ka.x * qq.x + ka.y * qq.y;
  #pragma unroll
  for (int off = SUB / 2; off >= 1; off >>= 1) s += __shfl_xor(s, off, 64);
  if (sl % SUB == 0) {
    const int h = sl / SUB;
    constexpr float scale = (DH == 32) ? 0.17677669529663687f : 0.25f;
    exb[(size_t)j * HH + h] = __expf(s * prior[r * HH + h] * scale);
  }
}

// ---------------- E2: per-node gather aggregation ----------------
template<int D, int DH>
__global__ __launch_bounds__(256) void node_aggr(
    const float* __restrict__ vM, const int* __restrict__ rowptr,
    const int* __restrict__ srcrel, const float* __restrict__ exb,
    float* __restrict__ ag)
{
  const int lane = threadIdx.x & 63;
  const int n = blockIdx.x * 4 + (threadIdx.x >> 6);
  if (n >= NN) return;
  int j0 = clampi(rowptr[n], 0, ETOT);
  int j1 = clampi(rowptr[n + 1], j0, ETOT);
  if (D == 128) {
    const int h = lane >> 4;
    float2 acc = make_float2(0.f, 0.f);
    float den = 0.f;
    for (int j = j0; j < j1; ++j) {
      const int word = srcrel[j];
      const int src = clampi(word & 0xFFFFFF, 0, NN - 1);
      const int r = clampi(word >> 24, 0, RR - 1);
      const float ex = exb[(size_t)j * HH + h];
      const float2 vm = *(const float2*)&vM[(size_t)src * (RR * D) + r * D + lane * 2];
      den += ex;
      acc.x = fmaf(ex, vm.x, acc.x);
      acc.y = fmaf(ex, vm.y, acc.y);
    }
    const float inv = 1.f / (den + 1e-9f);
    *(float2*)&ag[(size_t)n * D + lane * 2] = make_float2(acc.x * inv, acc.y * inv);
  } else {
    const int h = lane >> 4;
    float acc = 0.f;
    float den = 0.f;
    for (int j = j0; j < j1; ++j) {
      const int word = srcrel[j];
      const int src = clampi(word & 0xFFFFFF, 0, NN - 1);
      const int r = clampi(word >> 24, 0, RR - 1);
      const float ex = exb[(size_t)j * HH + h];
      den += ex;
      acc = fmaf(ex, vM[(size_t)src * (RR * D) + r * D + lane], acc);
    }
    ag[(size_t)n * D + lane] = acc / (den + 1e-9f);
  }
}

extern "C" void kernel_launch(void* const* d_in, const int* in_sizes, int n_in,
                              void* d_out, int out_size, void* d_ws, size_t ws_size,
                              hipStream_t stream)
{
  const float* x   = (const float*)d_in[0];
  const int*   EI  = (const int*)  d_in[1];
  const float* Wk1 = (const float*)d_in[2];
  const float* Wq1 = (const float*)d_in[3];
  const float* Wv1 = (const float*)d_in[4];
  const float* A1  = (const float*)d_in[5];
  const float* M1  = (const float*)d_in[6];
  const float* P1  = (const float*)d_in[7];
  const float* Wo1 = (const float*)d_in[8];
  const float* Wk2 = (const float*)d_in[9];
  const float* Wq2 = (const float*)d_in[10];
  const float* Wv2 = (const float*)d_in[11];
  const float* A2  = (const float*)d_in[12];
  const float* M2  = (const float*)d_in[13];
  const float* P2  = (const float*)d_in[14];
  const float* Wo2 = (const float*)d_in[15];
  float* out = (float*)d_out;

  float* ws = (float*)d_ws;
  const size_t nd = (size_t)NN * 128;
  float* P  = ws;                  // 3*nd : kA / vM  (layer2: kA2 | vM2 halves)
  float* Q  = ws + 3 * nd;         // nd   : q, then ag
  float* Hb = ws + 4 * nd;         // nd   : layer-1 output; exb aliases while Hb dead
  // split-bf16 B buffers (16B-aligned: 5*nd*4 bytes from base)
  ushort* WBth = (ushort*)(ws + 5 * nd);   // 384*128
  ushort* WBtl = WBth + 49152;             // 384*128
  ushort* WTh  = WBtl + 49152;             // up to 128*128
  ushort* WTl  = WTh + 16384;              // up to 128*128
  int* ints   = (int*)(WTl + 16384);       // = ws + 5*nd + 65536 dwords
  int* rowptr = ints;              // NN+1
  int* cursor = rowptr + NN + 1;   // NN
  int* blks   = cursor + NN;       // 2*NB
  int* srcrel = blks + 2 * NB;     // ETOT
  int* dstA   = srcrel + ETOT;     // ETOT
  float* exb  = Hb;                // ETOT*HH floats inside Hb while Hb dead

  const size_t need_bytes = (5 * nd + 65536) * 4 +
      ((size_t)(NN + 1) + NN + 2 * NB + 2 * ETOT) * 4;
  if (ws_size < need_bytes) return;   // visible absmax failure, not a fault

  dim3 blk(256);

  // ---------- Layer 1 (D=128, dh=32) ----------
  convt<<<dim3(64), blk, 0, stream>>>(Wq1, WTh, WTl, 128, 128);
  gemm_sbf<<<dim3(782, 2), blk, 0, stream>>>(x, WTh, WTl, Q, NN, 128, 128, 0);

  // CSR build (shared by both layers)
  zero_i32<<<dim3(NB), blk, 0, stream>>>(cursor, NN);
  csr_count<<<dim3((ETOT + 255) / 256), blk, 0, stream>>>(EI, cursor);
  scan_intra<<<dim3(NB), blk, 0, stream>>>(cursor, blks);
  scan_mid<<<dim3(1), blk, 0, stream>>>(blks, blks + NB);
  scan_add<<<dim3(NB), blk, 0, stream>>>(cursor, blks + NB, rowptr, cursor);
  csr_scatter<<<dim3((ETOT + 255) / 256), blk, 0, stream>>>(EI, cursor, srcrel, dstA);

  build_wT<<<dim3(192), blk, 0, stream>>>(Wk1, A1, WBth, WBtl, 128, 128, 32);
  gemm_sbf<<<dim3(782, 6), blk, 0, stream>>>(x, WBth, WBtl, P, NN, 384, 128, 0);
  edge_score<128, 32><<<dim3((ETOT + 3) / 4), blk, 0, stream>>>(P, Q, srcrel, dstA, P1, exb);
  build_wT<<<dim3(192), blk, 0, stream>>>(Wv1, M1, WBth, WBtl, 128, 128, 32);
  gemm_sbf<<<dim3(782, 6), blk, 0, stream>>>(x, WBth, WBtl, P, NN, 384, 128, 0);
  node_aggr<128, 32><<<dim3((NN + 3) / 4), blk, 0, stream>>>(P, rowptr, srcrel, exb, Q);
  convt<<<dim3(64), blk, 0, stream>>>(Wo1, WTh, WTl, 128, 128);
  gemm_sbf<<<dim3(782, 2), blk, 0, stream>>>(Q, WTh, WTl, Hb, NN, 128, 128, 1); // relu; exb dead

  // ---------- Layer 2 (D=64, dh=16): all Hb readers before exb overwrites Hb ----------
  build_wT<<<dim3(96), blk, 0, stream>>>(Wk2, A2, WBth, WBtl, 128, 64, 16);
  gemm_sbf<<<dim3(782, 3), blk, 0, stream>>>(Hb, WBth, WBtl, P, NN, 192, 128, 0);            // kA2
  build_wT<<<dim3(96), blk, 0, stream>>>(Wv2, M2, WBth, WBtl, 128, 64, 16);
  gemm_sbf<<<dim3(782, 3), blk, 0, stream>>>(Hb, WBth, WBtl, P + (size_t)NN * 192, NN, 192, 128, 0); // vM2
  convt<<<dim3(32), blk, 0, stream>>>(Wq2, WTh, WTl, 128, 64);
  gemm_sbf<<<dim3(782, 1), blk, 0, stream>>>(Hb, WTh, WTl, Q, NN, 64, 128, 0);               // q2
  edge_score<64, 16><<<dim3((ETOT + 7) / 8), blk, 0, stream>>>(P, Q, srcrel, dstA, P2, exb);
  float* ag2 = Q + nd / 2;
  node_aggr<64, 16><<<dim3((NN + 3) / 4), blk, 0, stream>>>(P + (size_t)NN * 192, rowptr, srcrel, exb, ag2);
  convt<<<dim3(16), blk, 0, stream>>>(Wo2, WTh, WTl, 64, 64);
  gemm_sbf<<<dim3(782, 1), blk, 0, stream>>>(ag2, WTh, WTl, out, NN, 64, 64, 0);
}

// Round 9
// 554.077 us; speedup vs baseline: 3.3198x; 1.3605x over previous
//
#include <hip/hip_runtime.h>

#define NN 100000
#define RR 3
#define EE 200000
#define HH 4
#define ETOT (RR * EE)
#define NB ((NN + 255) / 256)

typedef __attribute__((ext_vector_type(8))) short bf16x8;
typedef __attribute__((ext_vector_type(4))) float f32x4;

__device__ __forceinline__ int clampi(int v, int lo, int hi) {
  return v < lo ? lo : (v > hi ? hi : v);
}

// split fp32 -> bf16 hi + bf16 lo (RNE both): a ~= hi + lo, residual ~2^-18
__device__ __forceinline__ void split2(float v, ushort& h, ushort& l) {
  uint u = __float_as_uint(v);
  uint hb = (u + 0x7FFFu + ((u >> 16) & 1u)) >> 16;
  float fh = __uint_as_float(hb << 16);
  float r = v - fh;
  uint ur = __float_as_uint(r);
  uint lb = (ur + 0x7FFFu + ((ur >> 16) & 1u)) >> 16;
  h = (ushort)hb; l = (ushort)lb;
}

__device__ __forceinline__ ushort f2bf(float v) {
  uint u = __float_as_uint(v);
  return (ushort)((u + 0x7FFFu + ((u >> 16) & 1u)) >> 16);
}

// ---------------- split-bf16 MFMA GEMM: C[M,N] = A[M,K] @ B[K,N] ----------------
// A fp32 row-major (split in-kernel). B pre-split+transposed: Bth/Btl = [N][K] bf16.
// Tile 128x64, 256 thr = 4 waves, wave = 32 rows x 64 cols (2x4 16x16 frags).
// obf: write C as bf16 (ushort) instead of fp32.
__global__ __launch_bounds__(256) void gemm_sbf(
    const float* __restrict__ A, const ushort* __restrict__ Bth,
    const ushort* __restrict__ Btl, float* __restrict__ C,
    int M, int N, int K, int relu, int obf)
{
  __shared__ uint Bh[64 * 68];   // [col][K shorts padded to 136] as dwords
  __shared__ uint Bl[64 * 68];
  const int tid = threadIdx.x;
  const int m0 = blockIdx.x * 128, n0 = blockIdx.y * 64;

  {
    const int c = tid >> 2, kq = tid & 3;
    if (kq * 32 < K) {
      const uint4* sh = (const uint4*)(Bth + (size_t)(n0 + c) * K + kq * 32);
      const uint4* sl = (const uint4*)(Btl + (size_t)(n0 + c) * K + kq * 32);
      uint4* dh = (uint4*)&Bh[c * 68 + kq * 16];
      uint4* dl = (uint4*)&Bl[c * 68 + kq * 16];
      #pragma unroll
      for (int q = 0; q < 4; ++q) { dh[q] = sh[q]; dl[q] = sl[q]; }
    }
  }
  __syncthreads();

  const int lane = tid & 63, wv = tid >> 6;
  const int rbase = m0 + wv * 32 + (lane & 15);
  const int kof = (lane >> 4) * 8;

  f32x4 acc[2][4];
  #pragma unroll
  for (int m = 0; m < 2; ++m)
    #pragma unroll
    for (int n = 0; n < 4; ++n) acc[m][n] = (f32x4){0.f, 0.f, 0.f, 0.f};

  for (int kk = 0; kk < K; kk += 32) {
    const int kt = kk >> 5;
    bf16x8 ah[2], al[2];
    #pragma unroll
    for (int m = 0; m < 2; ++m) {
      const int row = rbase + m * 16;
      float4 a0 = make_float4(0.f, 0.f, 0.f, 0.f);
      float4 a1 = make_float4(0.f, 0.f, 0.f, 0.f);
      if (row < M) {
        const float4* ap = (const float4*)(A + (size_t)row * K + kk + kof);
        a0 = ap[0]; a1 = ap[1];
      }
      const float v[8] = {a0.x, a0.y, a0.z, a0.w, a1.x, a1.y, a1.z, a1.w};
      #pragma unroll
      for (int i = 0; i < 8; ++i) {
        ushort h, l; split2(v[i], h, l);
        ah[m][i] = (short)h; al[m][i] = (short)l;
      }
    }
    #pragma unroll
    for (int n = 0; n < 4; ++n) {
      const int boff = (n * 16 + (lane & 15)) * 68 + kt * 16 + (lane >> 4) * 4;
      uint4 uh = *(const uint4*)&Bh[boff];
      uint4 ul = *(const uint4*)&Bl[boff];
      bf16x8 bh = *reinterpret_cast<bf16x8*>(&uh);
      bf16x8 bl = *reinterpret_cast<bf16x8*>(&ul);
      #pragma unroll
      for (int m = 0; m < 2; ++m) {
        acc[m][n] = __builtin_amdgcn_mfma_f32_16x16x32_bf16(ah[m], bh, acc[m][n], 0, 0, 0);
        acc[m][n] = __builtin_amdgcn_mfma_f32_16x16x32_bf16(ah[m], bl, acc[m][n], 0, 0, 0);
        acc[m][n] = __builtin_amdgcn_mfma_f32_16x16x32_bf16(al[m], bh, acc[m][n], 0, 0, 0);
      }
    }
  }

  // C/D frag mapping (m89-verified): col = lane&15, row = (lane>>4)*4 + j
  #pragma unroll
  for (int m = 0; m < 2; ++m) {
    const int rw = m0 + wv * 32 + m * 16 + (lane >> 4) * 4;
    #pragma unroll
    for (int n = 0; n < 4; ++n) {
      const int col = n0 + n * 16 + (lane & 15);
      #pragma unroll
      for (int j = 0; j < 4; ++j) {
        if (rw + j < M) {
          float o = acc[m][n][j];
          if (relu) o = fmaxf(o, 0.f);
          if (obf) ((ushort*)C)[(size_t)(rw + j) * N + col] = f2bf(o);
          else     C[(size_t)(rw + j) * N + col] = o;
        }
      }
    }
  }
}

// ---------------- plain weight -> transposed split-bf16: W[K][N] -> T[N][K] hi/lo ----
__global__ __launch_bounds__(256) void convt(
    const float* __restrict__ W, ushort* __restrict__ Th, ushort* __restrict__ Tl,
    int K, int N)
{
  int idx = blockIdx.x * 256 + threadIdx.x;
  if (idx >= K * N) return;
  int n = idx / K, k = idx % K;
  ushort h, l; split2(W[(size_t)k * N + n], h, l);
  Th[(size_t)n * K + k] = h;
  Tl[(size_t)n * K + k] = l;
}

// ---------------- weight-space fusion -> transposed split-bf16 ----------------
__global__ __launch_bounds__(256) void build_wT(
    const float* __restrict__ W, const float* __restrict__ T,
    ushort* __restrict__ Oh, ushort* __restrict__ Ol, int F, int D, int dh)
{
  const int cols = RR * D;
  int idx = blockIdx.x * 256 + threadIdx.x;
  if (idx >= F * cols) return;
  int i = idx / cols, c = idx % cols;
  int r = c / D, gf = c % D;
  int h = gf / dh, f = gf % dh;
  const float* w = W + (size_t)i * D + h * dh;
  const float* t = T + ((size_t)(r * HH + h) * dh) * dh + f;
  float s = 0.f;
  for (int d = 0; d < dh; ++d) s = fmaf(w[d], t[(size_t)d * dh], s);
  ushort hh, ll; split2(s, hh, ll);
  Oh[(size_t)c * F + i] = hh;
  Ol[(size_t)c * F + i] = ll;
}

// ---------------- CSR build ----------------
__global__ __launch_bounds__(256) void zero_i32(int* __restrict__ p, int n)
{
  int i = blockIdx.x * 256 + threadIdx.x;
  if (i < n) p[i] = 0;
}

__global__ __launch_bounds__(256) void csr_count(
    const int* __restrict__ EI, int* __restrict__ cnt)
{
  int idx = blockIdx.x * 256 + threadIdx.x;
  if (idx >= ETOT) return;
  int r = idx / EE, e = idx % EE;
  int dst = clampi(EI[(size_t)r * 2 * EE + EE + e], 0, NN - 1);
  atomicAdd(&cnt[dst], 1);
}

__global__ __launch_bounds__(256) void scan_intra(
    int* __restrict__ arr, int* __restrict__ blksum)
{
  __shared__ int s[256];
  const int t = threadIdx.x;
  const int i = blockIdx.x * 256 + t;
  int v = (i < NN) ? arr[i] : 0;
  s[t] = v;
  __syncthreads();
  #pragma unroll
  for (int off = 1; off < 256; off <<= 1) {
    int x = (t >= off) ? s[t - off] : 0;
    __syncthreads();
    s[t] += x;
    __syncthreads();
  }
  if (i < NN) arr[i] = s[t] - v;        // exclusive
  if (t == 255) blksum[blockIdx.x] = s[255];
}

__global__ __launch_bounds__(256) void scan_mid(
    const int* __restrict__ blksum, int* __restrict__ blkoff)
{
  __shared__ int s[256];
  __shared__ int carry;
  const int t = threadIdx.x;
  if (t == 0) carry = 0;
  __syncthreads();
  for (int base = 0; base < NB; base += 256) {
    const int i = base + t;
    int v = (i < NB) ? blksum[i] : 0;
    s[t] = v;
    __syncthreads();
    #pragma unroll
    for (int off = 1; off < 256; off <<= 1) {
      int x = (t >= off) ? s[t - off] : 0;
      __syncthreads();
      s[t] += x;
      __syncthreads();
    }
    if (i < NB) blkoff[i] = carry + s[t] - v;   // global exclusive
    __syncthreads();
    if (t == 255) carry += s[255];
    __syncthreads();
  }
}

__global__ __launch_bounds__(256) void scan_add(
    int* __restrict__ arr, const int* __restrict__ blkoff,
    int* __restrict__ rowptr, int* __restrict__ cursor)
{
  int i = blockIdx.x * 256 + threadIdx.x;
  if (i < NN) {
    int v = arr[i] + blkoff[i >> 8];
    rowptr[i] = v;
    cursor[i] = v;
  }
  if (i == NN) rowptr[NN] = ETOT;
}

__global__ __launch_bounds__(256) void csr_scatter(
    const int* __restrict__ EI, int* __restrict__ cursor,
    int* __restrict__ srcrel)
{
  int idx = blockIdx.x * 256 + threadIdx.x;
  if (idx >= ETOT) return;
  int r = idx / EE, e = idx % EE;
  int src = clampi(EI[(size_t)r * 2 * EE + e], 0, NN - 1);
  int dst = clampi(EI[(size_t)r * 2 * EE + EE + e], 0, NN - 1);
  int pos = atomicAdd(&cursor[dst], 1);
  pos = clampi(pos, 0, ETOT - 1);
  srcrel[pos] = src | (r << 24);
}

// ---------------- fused per-node score+softmax+aggregate (no atomics) ----------
// kAb/vMb: bf16 [N][R*D]; qag: fp32 [N][D] holds q on entry, aggr output on exit.
// One node per D/2 lanes; q stays in registers; den accumulated in-loop.
template<int D, int DH>
__global__ __launch_bounds__(256) void node_fused(
    const ushort* __restrict__ kAb, const ushort* __restrict__ vMb,
    const int* __restrict__ rowptr, const int* __restrict__ srcrel,
    const float* __restrict__ prior, float* __restrict__ qag)
{
  constexpr int LPN = D / 2;      // lanes per node (2 feats each)
  constexpr int NPW = 64 / LPN;   // nodes per wave
  constexpr int SUB = DH / 2;     // lanes per head
  const int lane = threadIdx.x & 63;
  const int wv = blockIdx.x * 4 + (threadIdx.x >> 6);
  const int n = wv * NPW + lane / LPN;
  const int sl = lane % LPN;
  if (n >= NN) return;
  const int h = sl / SUB;
  constexpr float scale = (DH == 32) ? 0.17677669529663687f : 0.25f;
  float pr[RR];
  #pragma unroll
  for (int r = 0; r < RR; ++r) pr[r] = prior[r * HH + h] * scale;
  const float2 qq = *(const float2*)&qag[(size_t)n * D + sl * 2];
  const int j0 = clampi(rowptr[n], 0, ETOT);
  const int j1 = clampi(rowptr[n + 1], j0, ETOT);
  float2 acc = make_float2(0.f, 0.f);
  float den = 0.f;
  for (int j = j0; j < j1; ++j) {
    const int word = srcrel[j];
    const int src = clampi(word & 0xFFFFFF, 0, NN - 1);
    const int r = clampi(word >> 24, 0, RR - 1);
    const size_t base = (size_t)src * (RR * D) + r * D + sl * 2;
    const uint ku = *(const uint*)&kAb[base];   // 2 bf16
    const uint vu = *(const uint*)&vMb[base];   // issue both gathers up front
    const float kx = __uint_as_float(ku << 16);
    const float ky = __uint_as_float(ku & 0xFFFF0000u);
    const float vx = __uint_as_float(vu << 16);
    const float vy = __uint_as_float(vu & 0xFFFF0000u);
    float s = kx * qq.x + ky * qq.y;
    #pragma unroll
    for (int off = SUB / 2; off >= 1; off >>= 1) s += __shfl_xor(s, off, 64);
    const float ex = __expf(s * pr[r]);
    den += ex;
    acc.x = fmaf(ex, vx, acc.x);
    acc.y = fmaf(ex, vy, acc.y);
  }
  const float inv = 1.f / (den + 1e-9f);
  *(float2*)&qag[(size_t)n * D + sl * 2] = make_float2(acc.x * inv, acc.y * inv);
}

extern "C" void kernel_launch(void* const* d_in, const int* in_sizes, int n_in,
                              void* d_out, int out_size, void* d_ws, size_t ws_size,
                              hipStream_t stream)
{
  const float* x   = (const float*)d_in[0];
  const int*   EI  = (const int*)  d_in[1];
  const float* Wk1 = (const float*)d_in[2];
  const float* Wq1 = (const float*)d_in[3];
  const float* Wv1 = (const float*)d_in[4];
  const float* A1  = (const float*)d_in[5];
  const float* M1  = (const float*)d_in[6];
  const float* P1  = (const float*)d_in[7];
  const float* Wo1 = (const float*)d_in[8];
  const float* Wk2 = (const float*)d_in[9];
  const float* Wq2 = (const float*)d_in[10];
  const float* Wv2 = (const float*)d_in[11];
  const float* A2  = (const float*)d_in[12];
  const float* M2  = (const float*)d_in[13];
  const float* P2  = (const float*)d_in[14];
  const float* Wo2 = (const float*)d_in[15];
  float* out = (float*)d_out;

  float* ws = (float*)d_ws;
  const size_t nd = (size_t)NN * 128;
  // kA/vM bf16 buffers: N*384 ushorts each = 1.5*nd floats each (layer2: N*192)
  ushort* kAb = (ushort*)ws;
  ushort* vMb = (ushort*)(ws + 3 * nd / 2);
  float* Q  = ws + 3 * nd;         // q (fp32), then aggr output (same rows)
  float* Hb = ws + 4 * nd;         // layer-1 output
  ushort* WBth = (ushort*)(ws + 5 * nd);   // 384*128
  ushort* WBtl = WBth + 49152;
  ushort* WTh  = WBtl + 49152;             // up to 128*128
  ushort* WTl  = WTh + 16384;
  int* ints   = (int*)(WTl + 16384);       // = ws + 5*nd + 65536 dwords
  int* rowptr = ints;              // NN+1
  int* cursor = rowptr + NN + 1;   // NN
  int* blks   = cursor + NN;       // 2*NB
  int* srcrel = blks + 2 * NB;     // ETOT (src | r<<24, dst-sorted)

  const size_t need_bytes = (5 * nd + 65536) * 4 +
      ((size_t)(NN + 1) + NN + 2 * NB + ETOT) * 4;
  if (ws_size < need_bytes) return;   // visible absmax failure, not a fault

  dim3 blk(256);

  // ---------- Layer 1 (D=128, dh=32) ----------
  convt<<<dim3(64), blk, 0, stream>>>(Wq1, WTh, WTl, 128, 128);
  gemm_sbf<<<dim3(782, 2), blk, 0, stream>>>(x, WTh, WTl, Q, NN, 128, 128, 0, 0);  // q1 fp32

  // CSR build (shared by both layers)
  zero_i32<<<dim3(NB), blk, 0, stream>>>(cursor, NN);
  csr_count<<<dim3((ETOT + 255) / 256), blk, 0, stream>>>(EI, cursor);
  scan_intra<<<dim3(NB), blk, 0, stream>>>(cursor, blks);
  scan_mid<<<dim3(1), blk, 0, stream>>>(blks, blks + NB);
  scan_add<<<dim3(NB), blk, 0, stream>>>(cursor, blks + NB, rowptr, cursor);
  csr_scatter<<<dim3((ETOT + 255) / 256), blk, 0, stream>>>(EI, cursor, srcrel);

  build_wT<<<dim3(192), blk, 0, stream>>>(Wk1, A1, WBth, WBtl, 128, 128, 32);
  gemm_sbf<<<dim3(782, 6), blk, 0, stream>>>(x, WBth, WBtl, (float*)kAb, NN, 384, 128, 0, 1);
  build_wT<<<dim3(192), blk, 0, stream>>>(Wv1, M1, WBth, WBtl, 128, 128, 32);
  gemm_sbf<<<dim3(782, 6), blk, 0, stream>>>(x, WBth, WBtl, (float*)vMb, NN, 384, 128, 0, 1);
  node_fused<128, 32><<<dim3((NN + 3) / 4), blk, 0, stream>>>(kAb, vMb, rowptr, srcrel, P1, Q);
  convt<<<dim3(64), blk, 0, stream>>>(Wo1, WTh, WTl, 128, 128);
  gemm_sbf<<<dim3(782, 2), blk, 0, stream>>>(Q, WTh, WTl, Hb, NN, 128, 128, 1, 0);  // relu

  // ---------- Layer 2 (D=64, dh=16) ----------
  build_wT<<<dim3(96), blk, 0, stream>>>(Wk2, A2, WBth, WBtl, 128, 64, 16);
  gemm_sbf<<<dim3(782, 3), blk, 0, stream>>>(Hb, WBth, WBtl, (float*)kAb, NN, 192, 128, 0, 1);
  build_wT<<<dim3(96), blk, 0, stream>>>(Wv2, M2, WBth, WBtl, 128, 64, 16);
  gemm_sbf<<<dim3(782, 3), blk, 0, stream>>>(Hb, WBth, WBtl, (float*)vMb, NN, 192, 128, 0, 1);
  convt<<<dim3(32), blk, 0, stream>>>(Wq2, WTh, WTl, 128, 64);
  gemm_sbf<<<dim3(782, 1), blk, 0, stream>>>(Hb, WTh, WTl, Q, NN, 64, 128, 0, 0);  // q2 fp32
  node_fused<64, 16><<<dim3((NN + 7) / 8), blk, 0, stream>>>(kAb, vMb, rowptr, srcrel, P2, Q);
  convt<<<dim3(16), blk, 0, stream>>>(Wo2, WTh, WTl, 64, 64);
  gemm_sbf<<<dim3(782, 1), blk, 0, stream>>>(Q, WTh, WTl, out, NN, 64, 64, 0, 0);
}

// Round 10
// 475.528 us; speedup vs baseline: 3.8681x; 1.1652x over previous
//
#include <hip/hip_runtime.h>

#define NN 100000
#define RR 3
#define EE 200000
#define HH 4
#define ETOT (RR * EE)
#define NB ((NN + 255) / 256)

typedef __attribute__((ext_vector_type(8))) short bf16x8;
typedef __attribute__((ext_vector_type(4))) float f32x4;

__device__ __forceinline__ int clampi(int v, int lo, int hi) {
  return v < lo ? lo : (v > hi ? hi : v);
}

// split fp32 -> bf16 hi + bf16 lo (RNE both): a ~= hi + lo, residual ~2^-18
__device__ __forceinline__ void split2(float v, ushort& h, ushort& l) {
  uint u = __float_as_uint(v);
  uint hb = (u + 0x7FFFu + ((u >> 16) & 1u)) >> 16;
  float fh = __uint_as_float(hb << 16);
  float r = v - fh;
  uint ur = __float_as_uint(r);
  uint lb = (ur + 0x7FFFu + ((ur >> 16) & 1u)) >> 16;
  h = (ushort)hb; l = (ushort)lb;
}

__device__ __forceinline__ ushort f2bf(float v) {
  uint u = __float_as_uint(v);
  return (ushort)((u + 0x7FFFu + ((u >> 16) & 1u)) >> 16);
}

// ---------------- persistent-A split-bf16 MFMA GEMM ----------------
// A fp32 [M][K] loaded ONCE into registers per 128-row block; loops over the
// concatenated B [NTOT][K] (pre-split hi/lo, transposed) in 64-col chunks.
// Outputs routed per chunk: cols [0,n0c) -> o0 bf16, [n0c,n0c+n1c) -> o1 bf16,
// rest -> o2 fp32 (optional relu). 3 MFMAs per term: hh + hl + lh.
template<int KT>   // K = KT*32
__global__ __launch_bounds__(256) void gemm_pa(
    const float* __restrict__ A,
    const ushort* __restrict__ Bth, const ushort* __restrict__ Btl,
    int M, int NTOT,
    ushort* __restrict__ o0, int n0c,
    ushort* __restrict__ o1, int n1c,
    float* __restrict__ o2, int n2c, int relu2)
{
  constexpr int K = KT * 32;
  constexpr int LDB = KT * 16 + 4;        // dwords per col row (pad 4)
  __shared__ uint Bh[64 * LDB];
  __shared__ uint Bl[64 * LDB];
  const int tid = threadIdx.x;
  const int m0 = blockIdx.x * 128;
  const int lane = tid & 63, wv = tid >> 6;
  const int rbase = m0 + wv * 32 + (lane & 15);
  const int kof = (lane >> 4) * 8;

  // ---- load A tile once: 2 m-frags x KT k-tiles, split to bf16 hi/lo ----
  bf16x8 ah[2][KT], al[2][KT];
  #pragma unroll
  for (int m = 0; m < 2; ++m) {
    const int row = rbase + m * 16;
    #pragma unroll
    for (int kt = 0; kt < KT; ++kt) {
      float4 a0 = make_float4(0.f, 0.f, 0.f, 0.f);
      float4 a1 = make_float4(0.f, 0.f, 0.f, 0.f);
      if (row < M) {
        const float4* ap = (const float4*)(A + (size_t)row * K + kt * 32 + kof);
        a0 = ap[0]; a1 = ap[1];
      }
      const float v[8] = {a0.x, a0.y, a0.z, a0.w, a1.x, a1.y, a1.z, a1.w};
      #pragma unroll
      for (int i = 0; i < 8; ++i) {
        ushort h, l; split2(v[i], h, l);
        ah[m][kt][i] = (short)h; al[m][kt][i] = (short)l;
      }
    }
  }

  // ---- loop over 64-col B chunks ----
  for (int cb = 0; cb < NTOT; cb += 64) {
    {
      const int c = tid >> 2, kq = tid & 3;
      if (kq * 32 < K) {
        const uint4* sh = (const uint4*)(Bth + (size_t)(cb + c) * K + kq * 32);
        const uint4* sl = (const uint4*)(Btl + (size_t)(cb + c) * K + kq * 32);
        uint4* dh = (uint4*)&Bh[c * LDB + kq * 16];
        uint4* dl = (uint4*)&Bl[c * LDB + kq * 16];
        #pragma unroll
        for (int q = 0; q < 4; ++q) { dh[q] = sh[q]; dl[q] = sl[q]; }
      }
    }
    __syncthreads();

    f32x4 acc[2][4];
    #pragma unroll
    for (int m = 0; m < 2; ++m)
      #pragma unroll
      for (int n = 0; n < 4; ++n) acc[m][n] = (f32x4){0.f, 0.f, 0.f, 0.f};

    #pragma unroll
    for (int kt = 0; kt < KT; ++kt) {
      #pragma unroll
      for (int n = 0; n < 4; ++n) {
        const int boff = (n * 16 + (lane & 15)) * LDB + kt * 16 + (lane >> 4) * 4;
        uint4 uh = *(const uint4*)&Bh[boff];
        uint4 ul = *(const uint4*)&Bl[boff];
        bf16x8 bh = *reinterpret_cast<bf16x8*>(&uh);
        bf16x8 bl = *reinterpret_cast<bf16x8*>(&ul);
        #pragma unroll
        for (int m = 0; m < 2; ++m) {
          acc[m][n] = __builtin_amdgcn_mfma_f32_16x16x32_bf16(ah[m][kt], bh, acc[m][n], 0, 0, 0);
          acc[m][n] = __builtin_amdgcn_mfma_f32_16x16x32_bf16(ah[m][kt], bl, acc[m][n], 0, 0, 0);
          acc[m][n] = __builtin_amdgcn_mfma_f32_16x16x32_bf16(al[m][kt], bh, acc[m][n], 0, 0, 0);
        }
      }
    }

    // chunk-level output routing (chunk never straddles: n?c are multiples of 64)
    ushort* ob = o0; int stride = n0c, coff = cb; int isf32 = 0;
    if (cb >= n0c + n1c) { stride = n2c; coff = cb - n0c - n1c; isf32 = 1; }
    else if (cb >= n0c)  { ob = o1; stride = n1c; coff = cb - n0c; }

    #pragma unroll
    for (int m = 0; m < 2; ++m) {
      const int rw = m0 + wv * 32 + m * 16 + (lane >> 4) * 4;
      #pragma unroll
      for (int n = 0; n < 4; ++n) {
        const int col = coff + n * 16 + (lane & 15);
        #pragma unroll
        for (int j = 0; j < 4; ++j) {
          if (rw + j < M) {
            float o = acc[m][n][j];
            if (isf32) {
              if (relu2) o = fmaxf(o, 0.f);
              o2[(size_t)(rw + j) * stride + col] = o;
            } else {
              ob[(size_t)(rw + j) * stride + col] = f2bf(o);
            }
          }
        }
      }
    }
    __syncthreads();   // before restaging next chunk
  }
}

// ---------------- plain weight -> transposed split-bf16: W[K][N] -> T[N][K] ----
__global__ __launch_bounds__(256) void convt(
    const float* __restrict__ W, ushort* __restrict__ Th, ushort* __restrict__ Tl,
    int K, int N)
{
  int idx = blockIdx.x * 256 + threadIdx.x;
  if (idx >= K * N) return;
  int n = idx / K, k = idx % K;
  ushort h, l; split2(W[(size_t)k * N + n], h, l);
  Th[(size_t)n * K + k] = h;
  Tl[(size_t)n * K + k] = l;
}

// ---------------- weight-space fusion -> transposed split-bf16 ----------------
__global__ __launch_bounds__(256) void build_wT(
    const float* __restrict__ W, const float* __restrict__ T,
    ushort* __restrict__ Oh, ushort* __restrict__ Ol, int F, int D, int dh)
{
  const int cols = RR * D;
  int idx = blockIdx.x * 256 + threadIdx.x;
  if (idx >= F * cols) return;
  int i = idx / cols, c = idx % cols;
  int r = c / D, gf = c % D;
  int h = gf / dh, f = gf % dh;
  const float* w = W + (size_t)i * D + h * dh;
  const float* t = T + ((size_t)(r * HH + h) * dh) * dh + f;
  float s = 0.f;
  for (int d = 0; d < dh; ++d) s = fmaf(w[d], t[(size_t)d * dh], s);
  ushort hh, ll; split2(s, hh, ll);
  Oh[(size_t)c * F + i] = hh;
  Ol[(size_t)c * F + i] = ll;
}

// ---------------- CSR build ----------------
__global__ __launch_bounds__(256) void zero_i32(int* __restrict__ p, int n)
{
  int i = blockIdx.x * 256 + threadIdx.x;
  if (i < n) p[i] = 0;
}

__global__ __launch_bounds__(256) void csr_count(
    const int* __restrict__ EI, int* __restrict__ cnt)
{
  int idx = blockIdx.x * 256 + threadIdx.x;
  if (idx >= ETOT) return;
  int r = idx / EE, e = idx % EE;
  int dst = clampi(EI[(size_t)r * 2 * EE + EE + e], 0, NN - 1);
  atomicAdd(&cnt[dst], 1);
}

__global__ __launch_bounds__(256) void scan_intra(
    int* __restrict__ arr, int* __restrict__ blksum)
{
  __shared__ int s[256];
  const int t = threadIdx.x;
  const int i = blockIdx.x * 256 + t;
  int v = (i < NN) ? arr[i] : 0;
  s[t] = v;
  __syncthreads();
  #pragma unroll
  for (int off = 1; off < 256; off <<= 1) {
    int x = (t >= off) ? s[t - off] : 0;
    __syncthreads();
    s[t] += x;
    __syncthreads();
  }
  if (i < NN) arr[i] = s[t] - v;        // exclusive
  if (t == 255) blksum[blockIdx.x] = s[255];
}

__global__ __launch_bounds__(256) void scan_mid(
    const int* __restrict__ blksum, int* __restrict__ blkoff)
{
  __shared__ int s[256];
  __shared__ int carry;
  const int t = threadIdx.x;
  if (t == 0) carry = 0;
  __syncthreads();
  for (int base = 0; base < NB; base += 256) {
    const int i = base + t;
    int v = (i < NB) ? blksum[i] : 0;
    s[t] = v;
    __syncthreads();
    #pragma unroll
    for (int off = 1; off < 256; off <<= 1) {
      int x = (t >= off) ? s[t - off] : 0;
      __syncthreads();
      s[t] += x;
      __syncthreads();
    }
    if (i < NB) blkoff[i] = carry + s[t] - v;   // global exclusive
    __syncthreads();
    if (t == 255) carry += s[255];
    __syncthreads();
  }
}

__global__ __launch_bounds__(256) void scan_add(
    int* __restrict__ arr, const int* __restrict__ blkoff,
    int* __restrict__ rowptr, int* __restrict__ cursor)
{
  int i = blockIdx.x * 256 + threadIdx.x;
  if (i < NN) {
    int v = arr[i] + blkoff[i >> 8];
    rowptr[i] = v;
    cursor[i] = v;
  }
  if (i == NN) rowptr[NN] = ETOT;
}

__global__ __launch_bounds__(256) void csr_scatter(
    const int* __restrict__ EI, int* __restrict__ cursor,
    int* __restrict__ srcrel)
{
  int idx = blockIdx.x * 256 + threadIdx.x;
  if (idx >= ETOT) return;
  int r = idx / EE, e = idx % EE;
  int src = clampi(EI[(size_t)r * 2 * EE + e], 0, NN - 1);
  int dst = clampi(EI[(size_t)r * 2 * EE + EE + e], 0, NN - 1);
  int pos = atomicAdd(&cursor[dst], 1);
  pos = clampi(pos, 0, ETOT - 1);
  srcrel[pos] = src | (r << 24);
}

// ---------------- fused per-node score+softmax+aggregate (unroll-2) ----------
template<int D, int DH>
__global__ __launch_bounds__(256) void node_fused(
    const ushort* __restrict__ kAb, const ushort* __restrict__ vMb,
    const int* __restrict__ rowptr, const int* __restrict__ srcrel,
    const float* __restrict__ prior, float* __restrict__ qag)
{
  constexpr int LPN = D / 2;      // lanes per node (2 feats each)
  constexpr int NPW = 64 / LPN;   // nodes per wave
  constexpr int SUB = DH / 2;     // lanes per head
  const int lane = threadIdx.x & 63;
  const int wv = blockIdx.x * 4 + (threadIdx.x >> 6);
  const int n = wv * NPW + lane / LPN;
  const int sl = lane % LPN;
  if (n >= NN) return;
  const int h = sl / SUB;
  constexpr float scale = (DH == 32) ? 0.17677669529663687f : 0.25f;
  float pr[RR];
  #pragma unroll
  for (int r = 0; r < RR; ++r) pr[r] = prior[r * HH + h] * scale;
  const float2 qq = *(const float2*)&qag[(size_t)n * D + sl * 2];
  const int j0 = clampi(rowptr[n], 0, ETOT);
  const int j1 = clampi(rowptr[n + 1], j0, ETOT);
  float2 acc = make_float2(0.f, 0.f);
  float den = 0.f;
  int j = j0;
  for (; j + 1 < j1; j += 2) {           // pairwise: 4 gathers in flight,
    const int w0 = srcrel[j];            // two interleaved shfl chains
    const int w1 = srcrel[j + 1];
    const int s0i = clampi(w0 & 0xFFFFFF, 0, NN - 1);
    const int r0  = clampi(w0 >> 24, 0, RR - 1);
    const int s1i = clampi(w1 & 0xFFFFFF, 0, NN - 1);
    const int r1  = clampi(w1 >> 24, 0, RR - 1);
    const size_t b0 = (size_t)s0i * (RR * D) + r0 * D + sl * 2;
    const size_t b1 = (size_t)s1i * (RR * D) + r1 * D + sl * 2;
    const uint ku0 = *(const uint*)&kAb[b0];
    const uint vu0 = *(const uint*)&vMb[b0];
    const uint ku1 = *(const uint*)&kAb[b1];
    const uint vu1 = *(const uint*)&vMb[b1];
    float s0 = __uint_as_float(ku0 << 16) * qq.x + __uint_as_float(ku0 & 0xFFFF0000u) * qq.y;
    float s1 = __uint_as_float(ku1 << 16) * qq.x + __uint_as_float(ku1 & 0xFFFF0000u) * qq.y;
    #pragma unroll
    for (int off = SUB / 2; off >= 1; off >>= 1) {
      s0 += __shfl_xor(s0, off, 64);
      s1 += __shfl_xor(s1, off, 64);
    }
    const float ex0 = __expf(s0 * pr[r0]);
    const float ex1 = __expf(s1 * pr[r1]);
    den += ex0 + ex1;
    acc.x = fmaf(ex0, __uint_as_float(vu0 << 16), acc.x);
    acc.y = fmaf(ex0, __uint_as_float(vu0 & 0xFFFF0000u), acc.y);
    acc.x = fmaf(ex1, __uint_as_float(vu1 << 16), acc.x);
    acc.y = fmaf(ex1, __uint_as_float(vu1 & 0xFFFF0000u), acc.y);
  }
  if (j < j1) {
    const int w0 = srcrel[j];
    const int s0i = clampi(w0 & 0xFFFFFF, 0, NN - 1);
    const int r0  = clampi(w0 >> 24, 0, RR - 1);
    const size_t b0 = (size_t)s0i * (RR * D) + r0 * D + sl * 2;
    const uint ku0 = *(const uint*)&kAb[b0];
    const uint vu0 = *(const uint*)&vMb[b0];
    float s0 = __uint_as_float(ku0 << 16) * qq.x + __uint_as_float(ku0 & 0xFFFF0000u) * qq.y;
    #pragma unroll
    for (int off = SUB / 2; off >= 1; off >>= 1) s0 += __shfl_xor(s0, off, 64);
    const float ex0 = __expf(s0 * pr[r0]);
    den += ex0;
    acc.x = fmaf(ex0, __uint_as_float(vu0 << 16), acc.x);
    acc.y = fmaf(ex0, __uint_as_float(vu0 & 0xFFFF0000u), acc.y);
  }
  const float inv = 1.f / (den + 1e-9f);
  *(float2*)&qag[(size_t)n * D + sl * 2] = make_float2(acc.x * inv, acc.y * inv);
}

extern "C" void kernel_launch(void* const* d_in, const int* in_sizes, int n_in,
                              void* d_out, int out_size, void* d_ws, size_t ws_size,
                              hipStream_t stream)
{
  const float* x   = (const float*)d_in[0];
  const int*   EI  = (const int*)  d_in[1];
  const float* Wk1 = (const float*)d_in[2];
  const float* Wq1 = (const float*)d_in[3];
  const float* Wv1 = (const float*)d_in[4];
  const float* A1  = (const float*)d_in[5];
  const float* M1  = (const float*)d_in[6];
  const float* P1  = (const float*)d_in[7];
  const float* Wo1 = (const float*)d_in[8];
  const float* Wk2 = (const float*)d_in[9];
  const float* Wq2 = (const float*)d_in[10];
  const float* Wv2 = (const float*)d_in[11];
  const float* A2  = (const float*)d_in[12];
  const float* M2  = (const float*)d_in[13];
  const float* P2  = (const float*)d_in[14];
  const float* Wo2 = (const float*)d_in[15];
  float* out = (float*)d_out;

  float* ws = (float*)d_ws;
  const size_t nd = (size_t)NN * 128;
  ushort* kAb = (ushort*)ws;                 // N*384 bf16 (L2: N*192)
  ushort* vMb = (ushort*)(ws + 3 * nd / 2);  // N*384 bf16
  float* Q  = ws + 3 * nd;                   // q fp32, then aggr (in-place)
  float* Hb = ws + 4 * nd;                   // layer-1 output
  ushort* WBth = (ushort*)(ws + 5 * nd);     // concat B hi: up to 896*128
  ushort* WBtl = WBth + 896 * 128;           // concat B lo
  int* ints   = (int*)(WBtl + 896 * 128);    // = ws + 5*nd + 114688 dwords
  int* rowptr = ints;              // NN+1
  int* cursor = rowptr + NN + 1;   // NN
  int* blks   = cursor + NN;       // 2*NB
  int* srcrel = blks + 2 * NB;     // ETOT (src | r<<24, dst-sorted)

  const size_t need_bytes = (5 * nd + 114688) * 4 +
      ((size_t)(NN + 1) + NN + 2 * NB + ETOT) * 4;
  if (ws_size < need_bytes) return;   // visible absmax failure, not a fault

  dim3 blk(256);
  const int GB = (NN + 127) / 128;    // 782 row-blocks

  // ---------- Layer 1 (D=128, dh=32) ----------
  // build concat B: rows [0,384)=kA1, [384,768)=vM1, [768,896)=q1
  build_wT<<<dim3(192), blk, 0, stream>>>(Wk1, A1, WBth, WBtl, 128, 128, 32);
  build_wT<<<dim3(192), blk, 0, stream>>>(Wv1, M1, WBth + 384 * 128, WBtl + 384 * 128, 128, 128, 32);
  convt<<<dim3(64), blk, 0, stream>>>(Wq1, WBth + 768 * 128, WBtl + 768 * 128, 128, 128);
  gemm_pa<4><<<dim3(GB), blk, 0, stream>>>(x, WBth, WBtl, NN, 896,
                                           kAb, 384, vMb, 384, Q, 128, 0);

  // CSR build (shared by both layers)
  zero_i32<<<dim3(NB), blk, 0, stream>>>(cursor, NN);
  csr_count<<<dim3((ETOT + 255) / 256), blk, 0, stream>>>(EI, cursor);
  scan_intra<<<dim3(NB), blk, 0, stream>>>(cursor, blks);
  scan_mid<<<dim3(1), blk, 0, stream>>>(blks, blks + NB);
  scan_add<<<dim3(NB), blk, 0, stream>>>(cursor, blks + NB, rowptr, cursor);
  csr_scatter<<<dim3((ETOT + 255) / 256), blk, 0, stream>>>(EI, cursor, srcrel);

  node_fused<128, 32><<<dim3((NN + 3) / 4), blk, 0, stream>>>(kAb, vMb, rowptr, srcrel, P1, Q);
  convt<<<dim3(64), blk, 0, stream>>>(Wo1, WBth, WBtl, 128, 128);
  gemm_pa<4><<<dim3(GB), blk, 0, stream>>>(Q, WBth, WBtl, NN, 128,
                                           (ushort*)nullptr, 0, (ushort*)nullptr, 0,
                                           Hb, 128, 1);   // relu

  // ---------- Layer 2 (D=64, dh=16) ----------
  // concat B: rows [0,192)=kA2, [192,384)=vM2, [384,448)=q2
  build_wT<<<dim3(96), blk, 0, stream>>>(Wk2, A2, WBth, WBtl, 128, 64, 16);
  build_wT<<<dim3(96), blk, 0, stream>>>(Wv2, M2, WBth + 192 * 128, WBtl + 192 * 128, 128, 64, 16);
  convt<<<dim3(32), blk, 0, stream>>>(Wq2, WBth + 384 * 128, WBtl + 384 * 128, 128, 64);
  gemm_pa<4><<<dim3(GB), blk, 0, stream>>>(Hb, WBth, WBtl, NN, 448,
                                           kAb, 192, vMb, 192, Q, 64, 0);

  node_fused<64, 16><<<dim3((NN + 7) / 8), blk, 0, stream>>>(kAb, vMb, rowptr, srcrel, P2, Q);
  convt<<<dim3(16), blk, 0, stream>>>(Wo2, WBth, WBtl, 64, 64);
  gemm_pa<2><<<dim3(GB), blk, 0, stream>>>(Q, WBth, WBtl, NN, 64,
                                           (ushort*)nullptr, 0, (ushort*)nullptr, 0,
                                           out, 64, 0);
}

// Round 11
// 473.682 us; speedup vs baseline: 3.8832x; 1.0039x over previous
//
#include <hip/hip_runtime.h>

#define NN 100000
#define RR 3
#define EE 200000
#define HH 4
#define ETOT (RR * EE)
#define NB ((NN + 255) / 256)

typedef __attribute__((ext_vector_type(8))) short bf16x8;
typedef __attribute__((ext_vector_type(4))) float f32x4;

__device__ __forceinline__ int clampi(int v, int lo, int hi) {
  return v < lo ? lo : (v > hi ? hi : v);
}

// split fp32 -> bf16 hi + bf16 lo (RNE both): a ~= hi + lo, residual ~2^-18
__device__ __forceinline__ void split2(float v, ushort& h, ushort& l) {
  uint u = __float_as_uint(v);
  uint hb = (u + 0x7FFFu + ((u >> 16) & 1u)) >> 16;
  float fh = __uint_as_float(hb << 16);
  float r = v - fh;
  uint ur = __float_as_uint(r);
  uint lb = (ur + 0x7FFFu + ((ur >> 16) & 1u)) >> 16;
  h = (ushort)hb; l = (ushort)lb;
}

__device__ __forceinline__ ushort f2bf(float v) {
  uint u = __float_as_uint(v);
  return (ushort)((u + 0x7FFFu + ((u >> 16) & 1u)) >> 16);
}

// ---------------- persistent-A split-bf16 MFMA GEMM, double-buffered LDS ------
// A fp32 [M][K] loaded ONCE into registers per 128-row block; loops over its
// y-slice of the concatenated B [NTOT][K] (pre-split hi/lo) in 64-col chunks,
// staging chunk c+1 into LDS buf^1 while computing chunk c (one barrier/chunk).
// Output routing: cols [0,nkv) -> kv even ushort (k), [nkv,2nkv) -> kv odd (v),
// rest -> o2 fp32 (optional relu).
template<int KT>   // K = KT*32
__global__ __launch_bounds__(256) void gemm_pa(
    const float* __restrict__ A,
    const ushort* __restrict__ Bth, const ushort* __restrict__ Btl,
    int M, int NTOT,
    ushort* __restrict__ kv, int nkv,
    float* __restrict__ o2, int n2c, int relu2)
{
  constexpr int K = KT * 32;
  constexpr int LDB = KT * 16 + 4;        // dwords per col row (pad 4)
  __shared__ uint Bh[2][64 * LDB];
  __shared__ uint Bl[2][64 * LDB];
  const int tid = threadIdx.x;
  const int m0 = blockIdx.x * 128;

  // y-slice chunk range
  const int nch = NTOT >> 6;
  const int hc = (nch + gridDim.y - 1) / gridDim.y;
  const int c0 = blockIdx.y * hc * 64;
  int c1 = c0 + hc * 64; if (c1 > NTOT) c1 = NTOT;
  if (c0 >= c1) return;

  const int lane = tid & 63, wv = tid >> 6;
  const int rbase = m0 + wv * 32 + (lane & 15);
  const int kof = (lane >> 4) * 8;

  // ---- load A tile once: 2 m-frags x KT k-tiles, split to bf16 hi/lo ----
  bf16x8 ah[2][KT], al[2][KT];
  #pragma unroll
  for (int m = 0; m < 2; ++m) {
    const int row = rbase + m * 16;
    #pragma unroll
    for (int kt = 0; kt < KT; ++kt) {
      float4 a0 = make_float4(0.f, 0.f, 0.f, 0.f);
      float4 a1 = make_float4(0.f, 0.f, 0.f, 0.f);
      if (row < M) {
        const float4* ap = (const float4*)(A + (size_t)row * K + kt * 32 + kof);
        a0 = ap[0]; a1 = ap[1];
      }
      const float v[8] = {a0.x, a0.y, a0.z, a0.w, a1.x, a1.y, a1.z, a1.w};
      #pragma unroll
      for (int i = 0; i < 8; ++i) {
        ushort h, l; split2(v[i], h, l);
        ah[m][kt][i] = (short)h; al[m][kt][i] = (short)l;
      }
    }
  }

  // staging: thread t covers col c = t>>2, k-quarter kq = t&3 (4 uint4 each side)
  auto stage = [&](int cb, int b) {
    const int c = tid >> 2, kq = tid & 3;
    if (kq * 32 < K) {
      const uint4* sh = (const uint4*)(Bth + (size_t)(cb + c) * K + kq * 32);
      const uint4* sl = (const uint4*)(Btl + (size_t)(cb + c) * K + kq * 32);
      uint4* dh = (uint4*)&Bh[b][c * LDB + kq * 16];
      uint4* dl = (uint4*)&Bl[b][c * LDB + kq * 16];
      #pragma unroll
      for (int q = 0; q < 4; ++q) { dh[q] = sh[q]; dl[q] = sl[q]; }
    }
  };

  stage(c0, 0);
  __syncthreads();
  int buf = 0;

  for (int cb = c0; cb < c1; cb += 64) {
    if (cb + 64 < c1) stage(cb + 64, buf ^ 1);   // overlap with compute below

    f32x4 acc[2][4];
    #pragma unroll
    for (int m = 0; m < 2; ++m)
      #pragma unroll
      for (int n = 0; n < 4; ++n) acc[m][n] = (f32x4){0.f, 0.f, 0.f, 0.f};

    #pragma unroll
    for (int kt = 0; kt < KT; ++kt) {
      #pragma unroll
      for (int n = 0; n < 4; ++n) {
        const int boff = (n * 16 + (lane & 15)) * LDB + kt * 16 + (lane >> 4) * 4;
        uint4 uh = *(const uint4*)&Bh[buf][boff];
        uint4 ul = *(const uint4*)&Bl[buf][boff];
        bf16x8 bh = *reinterpret_cast<bf16x8*>(&uh);
        bf16x8 bl = *reinterpret_cast<bf16x8*>(&ul);
        #pragma unroll
        for (int m = 0; m < 2; ++m) {
          acc[m][n] = __builtin_amdgcn_mfma_f32_16x16x32_bf16(ah[m][kt], bh, acc[m][n], 0, 0, 0);
          acc[m][n] = __builtin_amdgcn_mfma_f32_16x16x32_bf16(ah[m][kt], bl, acc[m][n], 0, 0, 0);
          acc[m][n] = __builtin_amdgcn_mfma_f32_16x16x32_bf16(al[m][kt], bh, acc[m][n], 0, 0, 0);
        }
      }
    }

    // epilogue (chunk-uniform routing; C/D frag: col=lane&15, row=(lane>>4)*4+j)
    if (kv && cb < 2 * nkv) {
      const int isv = (cb >= nkv) ? 1 : 0;
      const int cbase = cb - (isv ? nkv : 0);
      #pragma unroll
      for (int m = 0; m < 2; ++m) {
        const int rw = m0 + wv * 32 + m * 16 + (lane >> 4) * 4;
        #pragma unroll
        for (int n = 0; n < 4; ++n) {
          const int col = cbase + n * 16 + (lane & 15);
          #pragma unroll
          for (int j = 0; j < 4; ++j) {
            if (rw + j < M)
              kv[(size_t)(rw + j) * (2 * nkv) + 2 * col + isv] = f2bf(acc[m][n][j]);
          }
        }
      }
    } else {
      const int cbase = cb - 2 * nkv;
      #pragma unroll
      for (int m = 0; m < 2; ++m) {
        const int rw = m0 + wv * 32 + m * 16 + (lane >> 4) * 4;
        #pragma unroll
        for (int n = 0; n < 4; ++n) {
          const int col = cbase + n * 16 + (lane & 15);
          #pragma unroll
          for (int j = 0; j < 4; ++j) {
            if (rw + j < M) {
              float o = acc[m][n][j];
              if (relu2) o = fmaxf(o, 0.f);
              o2[(size_t)(rw + j) * n2c + col] = o;
            }
          }
        }
      }
    }
    __syncthreads();   // staging writes drained + all reads of buf done
    buf ^= 1;
  }
}

// ---------------- plain weight -> transposed split-bf16: W[K][N] -> T[N][K] ----
__global__ __launch_bounds__(256) void convt(
    const float* __restrict__ W, ushort* __restrict__ Th, ushort* __restrict__ Tl,
    int K, int N)
{
  int idx = blockIdx.x * 256 + threadIdx.x;
  if (idx >= K * N) return;
  int n = idx / K, k = idx % K;
  ushort h, l; split2(W[(size_t)k * N + n], h, l);
  Th[(size_t)n * K + k] = h;
  Tl[(size_t)n * K + k] = l;
}

// ---------------- weight-space fusion -> transposed split-bf16 ----------------
__global__ __launch_bounds__(256) void build_wT(
    const float* __restrict__ W, const float* __restrict__ T,
    ushort* __restrict__ Oh, ushort* __restrict__ Ol, int F, int D, int dh)
{
  const int cols = RR * D;
  int idx = blockIdx.x * 256 + threadIdx.x;
  if (idx >= F * cols) return;
  int i = idx / cols, c = idx % cols;
  int r = c / D, gf = c % D;
  int h = gf / dh, f = gf % dh;
  const float* w = W + (size_t)i * D + h * dh;
  const float* t = T + ((size_t)(r * HH + h) * dh) * dh + f;
  float s = 0.f;
  for (int d = 0; d < dh; ++d) s = fmaf(w[d], t[(size_t)d * dh], s);
  ushort hh, ll; split2(s, hh, ll);
  Oh[(size_t)c * F + i] = hh;
  Ol[(size_t)c * F + i] = ll;
}

// ---------------- CSR build ----------------
__global__ __launch_bounds__(256) void zero_i32(int* __restrict__ p, int n)
{
  int i = blockIdx.x * 256 + threadIdx.x;
  if (i < n) p[i] = 0;
}

__global__ __launch_bounds__(256) void csr_count(
    const int* __restrict__ EI, int* __restrict__ cnt)
{
  int idx = blockIdx.x * 256 + threadIdx.x;
  if (idx >= ETOT) return;
  int r = idx / EE, e = idx % EE;
  int dst = clampi(EI[(size_t)r * 2 * EE + EE + e], 0, NN - 1);
  atomicAdd(&cnt[dst], 1);
}

__global__ __launch_bounds__(256) void scan_intra(
    int* __restrict__ arr, int* __restrict__ blksum)
{
  __shared__ int s[256];
  const int t = threadIdx.x;
  const int i = blockIdx.x * 256 + t;
  int v = (i < NN) ? arr[i] : 0;
  s[t] = v;
  __syncthreads();
  #pragma unroll
  for (int off = 1; off < 256; off <<= 1) {
    int x = (t >= off) ? s[t - off] : 0;
    __syncthreads();
    s[t] += x;
    __syncthreads();
  }
  if (i < NN) arr[i] = s[t] - v;        // exclusive
  if (t == 255) blksum[blockIdx.x] = s[255];
}

__global__ __launch_bounds__(256) void scan_mid(
    const int* __restrict__ blksum, int* __restrict__ blkoff)
{
  __shared__ int s[256];
  __shared__ int carry;
  const int t = threadIdx.x;
  if (t == 0) carry = 0;
  __syncthreads();
  for (int base = 0; base < NB; base += 256) {
    const int i = base + t;
    int v = (i < NB) ? blksum[i] : 0;
    s[t] = v;
    __syncthreads();
    #pragma unroll
    for (int off = 1; off < 256; off <<= 1) {
      int x = (t >= off) ? s[t - off] : 0;
      __syncthreads();
      s[t] += x;
      __syncthreads();
    }
    if (i < NB) blkoff[i] = carry + s[t] - v;   // global exclusive
    __syncthreads();
    if (t == 255) carry += s[255];
    __syncthreads();
  }
}

__global__ __launch_bounds__(256) void scan_add(
    int* __restrict__ arr, const int* __restrict__ blkoff,
    int* __restrict__ rowptr, int* __restrict__ cursor)
{
  int i = blockIdx.x * 256 + threadIdx.x;
  if (i < NN) {
    int v = arr[i] + blkoff[i >> 8];
    rowptr[i] = v;
    cursor[i] = v;
  }
  if (i == NN) rowptr[NN] = ETOT;
}

__global__ __launch_bounds__(256) void csr_scatter(
    const int* __restrict__ EI, int* __restrict__ cursor,
    int* __restrict__ srcrel)
{
  int idx = blockIdx.x * 256 + threadIdx.x;
  if (idx >= ETOT) return;
  int r = idx / EE, e = idx % EE;
  int src = clampi(EI[(size_t)r * 2 * EE + e], 0, NN - 1);
  int dst = clampi(EI[(size_t)r * 2 * EE + EE + e], 0, NN - 1);
  int pos = atomicAdd(&cursor[dst], 1);
  pos = clampi(pos, 0, ETOT - 1);
  srcrel[pos] = src | (r << 24);
}

// ---------------- fused per-node score+softmax+aggregate (unroll-2) ----------
// kvb: interleaved bf16 [N][RR*D][2] = (k,v) per feature -> ONE uint2 gather/edge.
template<int D, int DH>
__global__ __launch_bounds__(256) void node_fused(
    const ushort* __restrict__ kvb,
    const int* __restrict__ rowptr, const int* __restrict__ srcrel,
    const float* __restrict__ prior, float* __restrict__ qag)
{
  constexpr int LPN = D / 2;      // lanes per node (2 feats each)
  constexpr int NPW = 64 / LPN;   // nodes per wave
  constexpr int SUB = DH / 2;     // lanes per head
  const int lane = threadIdx.x & 63;
  const int wv = blockIdx.x * 4 + (threadIdx.x >> 6);
  const int n = wv * NPW + lane / LPN;
  const int sl = lane % LPN;
  if (n >= NN) return;
  const int h = sl / SUB;
  constexpr float scale = (DH == 32) ? 0.17677669529663687f : 0.25f;
  float pr[RR];
  #pragma unroll
  for (int r = 0; r < RR; ++r) pr[r] = prior[r * HH + h] * scale;
  const float2 qq = *(const float2*)&qag[(size_t)n * D + sl * 2];
  const int j0 = clampi(rowptr[n], 0, ETOT);
  const int j1 = clampi(rowptr[n + 1], j0, ETOT);
  float2 acc = make_float2(0.f, 0.f);
  float den = 0.f;
  int j = j0;
  for (; j + 1 < j1; j += 2) {
    const int w0 = srcrel[j];
    const int w1 = srcrel[j + 1];
    const int s0i = clampi(w0 & 0xFFFFFF, 0, NN - 1);
    const int r0  = clampi(w0 >> 24, 0, RR - 1);
    const int s1i = clampi(w1 & 0xFFFFFF, 0, NN - 1);
    const int r1  = clampi(w1 >> 24, 0, RR - 1);
    const uint2 kv0 = *(const uint2*)&kvb[((size_t)s0i * (RR * D) + r0 * D + sl * 2) * 2];
    const uint2 kv1 = *(const uint2*)&kvb[((size_t)s1i * (RR * D) + r1 * D + sl * 2) * 2];
    float s0 = __uint_as_float(kv0.x << 16) * qq.x + __uint_as_float(kv0.y << 16) * qq.y;
    float s1 = __uint_as_float(kv1.x << 16) * qq.x + __uint_as_float(kv1.y << 16) * qq.y;
    #pragma unroll
    for (int off = SUB / 2; off >= 1; off >>= 1) {
      s0 += __shfl_xor(s0, off, 64);
      s1 += __shfl_xor(s1, off, 64);
    }
    const float ex0 = __expf(s0 * pr[r0]);
    const float ex1 = __expf(s1 * pr[r1]);
    den += ex0 + ex1;
    acc.x = fmaf(ex0, __uint_as_float(kv0.x & 0xFFFF0000u), acc.x);
    acc.y = fmaf(ex0, __uint_as_float(kv0.y & 0xFFFF0000u), acc.y);
    acc.x = fmaf(ex1, __uint_as_float(kv1.x & 0xFFFF0000u), acc.x);
    acc.y = fmaf(ex1, __uint_as_float(kv1.y & 0xFFFF0000u), acc.y);
  }
  if (j < j1) {
    const int w0 = srcrel[j];
    const int s0i = clampi(w0 & 0xFFFFFF, 0, NN - 1);
    const int r0  = clampi(w0 >> 24, 0, RR - 1);
    const uint2 kv0 = *(const uint2*)&kvb[((size_t)s0i * (RR * D) + r0 * D + sl * 2) * 2];
    float s0 = __uint_as_float(kv0.x << 16) * qq.x + __uint_as_float(kv0.y << 16) * qq.y;
    #pragma unroll
    for (int off = SUB / 2; off >= 1; off >>= 1) s0 += __shfl_xor(s0, off, 64);
    const float ex0 = __expf(s0 * pr[r0]);
    den += ex0;
    acc.x = fmaf(ex0, __uint_as_float(kv0.x & 0xFFFF0000u), acc.x);
    acc.y = fmaf(ex0, __uint_as_float(kv0.y & 0xFFFF0000u), acc.y);
  }
  const float inv = 1.f / (den + 1e-9f);
  *(float2*)&qag[(size_t)n * D + sl * 2] = make_float2(acc.x * inv, acc.y * inv);
}

extern "C" void kernel_launch(void* const* d_in, const int* in_sizes, int n_in,
                              void* d_out, int out_size, void* d_ws, size_t ws_size,
                              hipStream_t stream)
{
  const float* x   = (const float*)d_in[0];
  const int*   EI  = (const int*)  d_in[1];
  const float* Wk1 = (const float*)d_in[2];
  const float* Wq1 = (const float*)d_in[3];
  const float* Wv1 = (const float*)d_in[4];
  const float* A1  = (const float*)d_in[5];
  const float* M1  = (const float*)d_in[6];
  const float* P1  = (const float*)d_in[7];
  const float* Wo1 = (const float*)d_in[8];
  const float* Wk2 = (const float*)d_in[9];
  const float* Wq2 = (const float*)d_in[10];
  const float* Wv2 = (const float*)d_in[11];
  const float* A2  = (const float*)d_in[12];
  const float* M2  = (const float*)d_in[13];
  const float* P2  = (const float*)d_in[14];
  const float* Wo2 = (const float*)d_in[15];
  float* out = (float*)d_out;

  float* ws = (float*)d_ws;
  const size_t nd = (size_t)NN * 128;
  ushort* kvb = (ushort*)ws;                 // N*768 ushorts (L1) = 3*nd floats
  float* Q  = ws + 3 * nd;                   // q fp32, then aggr (in-place)
  float* Hb = ws + 4 * nd;                   // layer-1 output
  ushort* WBth = (ushort*)(ws + 5 * nd);     // concat B hi: up to 896*128
  ushort* WBtl = WBth + 896 * 128;           // concat B lo
  int* ints   = (int*)(WBtl + 896 * 128);    // = ws + 5*nd + 114688 dwords
  int* rowptr = ints;              // NN+1
  int* cursor = rowptr + NN + 1;   // NN
  int* blks   = cursor + NN;       // 2*NB
  int* srcrel = blks + 2 * NB;     // ETOT (src | r<<24, dst-sorted)

  const size_t need_bytes = (5 * nd + 114688) * 4 +
      ((size_t)(NN + 1) + NN + 2 * NB + ETOT) * 4;
  if (ws_size < need_bytes) return;   // visible absmax failure, not a fault

  dim3 blk(256);
  const int GB = (NN + 127) / 128;    // 782 row-blocks

  // ---------- Layer 1 (D=128, dh=32) ----------
  // concat B: rows [0,384)=kA1, [384,768)=vM1, [768,896)=q1
  build_wT<<<dim3(192), blk, 0, stream>>>(Wk1, A1, WBth, WBtl, 128, 128, 32);
  build_wT<<<dim3(192), blk, 0, stream>>>(Wv1, M1, WBth + 384 * 128, WBtl + 384 * 128, 128, 128, 32);
  convt<<<dim3(64), blk, 0, stream>>>(Wq1, WBth + 768 * 128, WBtl + 768 * 128, 128, 128);
  gemm_pa<4><<<dim3(GB, 2), blk, 0, stream>>>(x, WBth, WBtl, NN, 896,
                                              kvb, 384, Q, 128, 0);

  // CSR build (shared by both layers)
  zero_i32<<<dim3(NB), blk, 0, stream>>>(cursor, NN);
  csr_count<<<dim3((ETOT + 255) / 256), blk, 0, stream>>>(EI, cursor);
  scan_intra<<<dim3(NB), blk, 0, stream>>>(cursor, blks);
  scan_mid<<<dim3(1), blk, 0, stream>>>(blks, blks + NB);
  scan_add<<<dim3(NB), blk, 0, stream>>>(cursor, blks + NB, rowptr, cursor);
  csr_scatter<<<dim3((ETOT + 255) / 256), blk, 0, stream>>>(EI, cursor, srcrel);

  node_fused<128, 32><<<dim3((NN + 3) / 4), blk, 0, stream>>>(kvb, rowptr, srcrel, P1, Q);
  convt<<<dim3(64), blk, 0, stream>>>(Wo1, WBth, WBtl, 128, 128);
  gemm_pa<4><<<dim3(GB, 1), blk, 0, stream>>>(Q, WBth, WBtl, NN, 128,
                                              (ushort*)nullptr, 0, Hb, 128, 1);  // relu

  // ---------- Layer 2 (D=64, dh=16) ----------
  // concat B: rows [0,192)=kA2, [192,384)=vM2, [384,448)=q2
  build_wT<<<dim3(96), blk, 0, stream>>>(Wk2, A2, WBth, WBtl, 128, 64, 16);
  build_wT<<<dim3(96), blk, 0, stream>>>(Wv2, M2, WBth + 192 * 128, WBtl + 192 * 128, 128, 64, 16);
  convt<<<dim3(32), blk, 0, stream>>>(Wq2, WBth + 384 * 128, WBtl + 384 * 128, 128, 64);
  gemm_pa<4><<<dim3(GB, 2), blk, 0, stream>>>(Hb, WBth, WBtl, NN, 448,
                                              kvb, 192, Q, 64, 0);

  node_fused<64, 16><<<dim3((NN + 7) / 8), blk, 0, stream>>>(kvb, rowptr, srcrel, P2, Q);
  convt<<<dim3(16), blk, 0, stream>>>(Wo2, WBth, WBtl, 64, 64);
  gemm_pa<2><<<dim3(GB, 1), blk, 0, stream>>>(Q, WBth, WBtl, NN, 64,
                                              (ushort*)nullptr, 0, out, 64, 0);
}

// Round 12
// 416.759 us; speedup vs baseline: 4.4136x; 1.1366x over previous
//
#include <hip/hip_runtime.h>

#define NN 100000
#define RR 3
#define EE 200000
#define HH 4
#define ETOT (RR * EE)
#define NB ((NN + 255) / 256)

typedef __attribute__((ext_vector_type(8))) short bf16x8;
typedef __attribute__((ext_vector_type(4))) float f32x4;

__device__ __forceinline__ int clampi(int v, int lo, int hi) {
  return v < lo ? lo : (v > hi ? hi : v);
}

// split fp32 -> bf16 hi + bf16 lo (RNE both): a ~= hi + lo, residual ~2^-18
__device__ __forceinline__ void split2(float v, ushort& h, ushort& l) {
  uint u = __float_as_uint(v);
  uint hb = (u + 0x7FFFu + ((u >> 16) & 1u)) >> 16;
  float fh = __uint_as_float(hb << 16);
  float r = v - fh;
  uint ur = __float_as_uint(r);
  uint lb = (ur + 0x7FFFu + ((ur >> 16) & 1u)) >> 16;
  h = (ushort)hb; l = (ushort)lb;
}

__device__ __forceinline__ ushort f2bf(float v) {
  uint u = __float_as_uint(v);
  return (ushort)((u + 0x7FFFu + ((u >> 16) & 1u)) >> 16);
}

// ---------------- split x -> bf16 hi/lo planes ----------------
__global__ __launch_bounds__(256) void split_a(
    const float* __restrict__ A, ushort* __restrict__ Ah, ushort* __restrict__ Al,
    int total8)   // total elements / 8
{
  int idx = blockIdx.x * 256 + threadIdx.x;
  if (idx >= total8) return;
  const float4* ap = (const float4*)(A + (size_t)idx * 8);
  float4 a0 = ap[0], a1 = ap[1];
  const float v[8] = {a0.x, a0.y, a0.z, a0.w, a1.x, a1.y, a1.z, a1.w};
  ushort h[8], l[8];
  #pragma unroll
  for (int i = 0; i < 8; ++i) split2(v[i], h[i], l[i]);
  *(uint4*)(Ah + (size_t)idx * 8) = *(const uint4*)h;
  *(uint4*)(Al + (size_t)idx * 8) = *(const uint4*)l;
}

// ---------------- pure-bf16 persistent-A GEMM (1 MFMA/tile) for kv outputs ----
// A bf16 [M][K] (hi plane); B bf16 [NTOT][K] (hi). Cols [0,nk)->kb, [nk,2nk)->vb
// (both planar bf16, stride nk). Double-buffered LDS (hi only: 4 blocks/CU).
template<int KT>   // K = KT*32
__global__ __launch_bounds__(256) void gemm_bf1(
    const ushort* __restrict__ Ah, const ushort* __restrict__ Bth,
    int M, int NTOT,
    ushort* __restrict__ kb, int nk, ushort* __restrict__ vb)
{
  constexpr int K = KT * 32;
  constexpr int LDB = KT * 16 + 4;
  __shared__ uint Bs[2][64 * LDB];
  const int tid = threadIdx.x;
  const int m0 = blockIdx.x * 128;
  const int lane = tid & 63, wv = tid >> 6;
  const int rbase = m0 + wv * 32 + (lane & 15);
  const int kof = (lane >> 4) * 8;

  bf16x8 a[2][KT];
  #pragma unroll
  for (int m = 0; m < 2; ++m) {
    const int row = rbase + m * 16;
    #pragma unroll
    for (int kt = 0; kt < KT; ++kt) {
      uint4 u = make_uint4(0, 0, 0, 0);
      if (row < M) u = *(const uint4*)(Ah + (size_t)row * K + kt * 32 + kof);
      a[m][kt] = *reinterpret_cast<bf16x8*>(&u);
    }
  }

  auto stage = [&](int cb, int b) {
    const int c = tid >> 2, kq = tid & 3;
    if (kq * 32 < K) {
      const uint4* s = (const uint4*)(Bth + (size_t)(cb + c) * K + kq * 32);
      uint4* d = (uint4*)&Bs[b][c * LDB + kq * 16];
      #pragma unroll
      for (int q = 0; q < 4; ++q) d[q] = s[q];
    }
  };
  stage(0, 0);
  __syncthreads();
  int buf = 0;

  for (int cb = 0; cb < NTOT; cb += 64) {
    if (cb + 64 < NTOT) stage(cb + 64, buf ^ 1);

    f32x4 acc[2][4];
    #pragma unroll
    for (int m = 0; m < 2; ++m)
      #pragma unroll
      for (int n = 0; n < 4; ++n) acc[m][n] = (f32x4){0.f, 0.f, 0.f, 0.f};

    #pragma unroll
    for (int kt = 0; kt < KT; ++kt) {
      #pragma unroll
      for (int n = 0; n < 4; ++n) {
        const int boff = (n * 16 + (lane & 15)) * LDB + kt * 16 + (lane >> 4) * 4;
        uint4 u = *(const uint4*)&Bs[buf][boff];
        bf16x8 b8 = *reinterpret_cast<bf16x8*>(&u);
        acc[0][n] = __builtin_amdgcn_mfma_f32_16x16x32_bf16(a[0][kt], b8, acc[0][n], 0, 0, 0);
        acc[1][n] = __builtin_amdgcn_mfma_f32_16x16x32_bf16(a[1][kt], b8, acc[1][n], 0, 0, 0);
      }
    }

    // epilogue: C/D frag col=lane&15, row=(lane>>4)*4+j
    const int isv = (cb >= nk) ? 1 : 0;
    ushort* ob = isv ? vb : kb;
    const int cbase = cb - (isv ? nk : 0);
    #pragma unroll
    for (int m = 0; m < 2; ++m) {
      const int rw = m0 + wv * 32 + m * 16 + (lane >> 4) * 4;
      #pragma unroll
      for (int n = 0; n < 4; ++n) {
        const int col = cbase + n * 16 + (lane & 15);
        #pragma unroll
        for (int j = 0; j < 4; ++j)
          if (rw + j < M) ob[(size_t)(rw + j) * nk + col] = f2bf(acc[m][n][j]);
      }
    }
    __syncthreads();
    buf ^= 1;
  }
}

// ---------------- split-bf16 persistent-A GEMM (3 MFMA/tile), small NTOT ------
// A = hi+lo planes; B = hi+lo. Output: oh/ol split-bf16 (with relu) if oh!=null,
// else of fp32. Single-buffer LDS (NTOT <= 128 -> at most 2 chunks).
template<int KT>
__global__ __launch_bounds__(256) void gemm_sp3(
    const ushort* __restrict__ Ah, const ushort* __restrict__ Al,
    const ushort* __restrict__ Bth, const ushort* __restrict__ Btl,
    int M, int NTOT,
    float* __restrict__ of, ushort* __restrict__ oh, ushort* __restrict__ ol,
    int relu)
{
  constexpr int K = KT * 32;
  constexpr int LDB = KT * 16 + 4;
  __shared__ uint Bh[64 * LDB];
  __shared__ uint Bl[64 * LDB];
  const int tid = threadIdx.x;
  const int m0 = blockIdx.x * 128;
  const int lane = tid & 63, wv = tid >> 6;
  const int rbase = m0 + wv * 32 + (lane & 15);
  const int kof = (lane >> 4) * 8;

  bf16x8 ah[2][KT], al[2][KT];
  #pragma unroll
  for (int m = 0; m < 2; ++m) {
    const int row = rbase + m * 16;
    #pragma unroll
    for (int kt = 0; kt < KT; ++kt) {
      uint4 uh = make_uint4(0, 0, 0, 0), ul = make_uint4(0, 0, 0, 0);
      if (row < M) {
        uh = *(const uint4*)(Ah + (size_t)row * K + kt * 32 + kof);
        ul = *(const uint4*)(Al + (size_t)row * K + kt * 32 + kof);
      }
      ah[m][kt] = *reinterpret_cast<bf16x8*>(&uh);
      al[m][kt] = *reinterpret_cast<bf16x8*>(&ul);
    }
  }

  for (int cb = 0; cb < NTOT; cb += 64) {
    {
      const int c = tid >> 2, kq = tid & 3;
      if (kq * 32 < K) {
        const uint4* sh = (const uint4*)(Bth + (size_t)(cb + c) * K + kq * 32);
        const uint4* sl = (const uint4*)(Btl + (size_t)(cb + c) * K + kq * 32);
        uint4* dh = (uint4*)&Bh[c * LDB + kq * 16];
        uint4* dl = (uint4*)&Bl[c * LDB + kq * 16];
        #pragma unroll
        for (int q = 0; q < 4; ++q) { dh[q] = sh[q]; dl[q] = sl[q]; }
      }
    }
    __syncthreads();

    f32x4 acc[2][4];
    #pragma unroll
    for (int m = 0; m < 2; ++m)
      #pragma unroll
      for (int n = 0; n < 4; ++n) acc[m][n] = (f32x4){0.f, 0.f, 0.f, 0.f};

    #pragma unroll
    for (int kt = 0; kt < KT; ++kt) {
      #pragma unroll
      for (int n = 0; n < 4; ++n) {
        const int boff = (n * 16 + (lane & 15)) * LDB + kt * 16 + (lane >> 4) * 4;
        uint4 uh = *(const uint4*)&Bh[boff];
        uint4 ul = *(const uint4*)&Bl[boff];
        bf16x8 bh = *reinterpret_cast<bf16x8*>(&uh);
        bf16x8 bl = *reinterpret_cast<bf16x8*>(&ul);
        #pragma unroll
        for (int m = 0; m < 2; ++m) {
          acc[m][n] = __builtin_amdgcn_mfma_f32_16x16x32_bf16(ah[m][kt], bh, acc[m][n], 0, 0, 0);
          acc[m][n] = __builtin_amdgcn_mfma_f32_16x16x32_bf16(ah[m][kt], bl, acc[m][n], 0, 0, 0);
          acc[m][n] = __builtin_amdgcn_mfma_f32_16x16x32_bf16(al[m][kt], bh, acc[m][n], 0, 0, 0);
        }
      }
    }

    #pragma unroll
    for (int m = 0; m < 2; ++m) {
      const int rw = m0 + wv * 32 + m * 16 + (lane >> 4) * 4;
      #pragma unroll
      for (int n = 0; n < 4; ++n) {
        const int col = cb + n * 16 + (lane & 15);
        #pragma unroll
        for (int j = 0; j < 4; ++j) {
          if (rw + j < M) {
            float o = acc[m][n][j];
            if (relu) o = fmaxf(o, 0.f);
            if (oh) {
              ushort h, l; split2(o, h, l);
              oh[(size_t)(rw + j) * NTOT + col] = h;
              ol[(size_t)(rw + j) * NTOT + col] = l;
            } else {
              of[(size_t)(rw + j) * NTOT + col] = o;
            }
          }
        }
      }
    }
    __syncthreads();
  }
}

// ---------------- plain weight -> transposed split-bf16: W[K][N] -> T[N][K] ----
__global__ __launch_bounds__(256) void convt(
    const float* __restrict__ W, ushort* __restrict__ Th, ushort* __restrict__ Tl,
    int K, int N)
{
  int idx = blockIdx.x * 256 + threadIdx.x;
  if (idx >= K * N) return;
  int n = idx / K, k = idx % K;
  ushort h, l; split2(W[(size_t)k * N + n], h, l);
  Th[(size_t)n * K + k] = h;
  Tl[(size_t)n * K + k] = l;
}

// ---------------- weight-space fusion -> transposed split-bf16 ----------------
__global__ __launch_bounds__(256) void build_wT(
    const float* __restrict__ W, const float* __restrict__ T,
    ushort* __restrict__ Oh, ushort* __restrict__ Ol, int F, int D, int dh)
{
  const int cols = RR * D;
  int idx = blockIdx.x * 256 + threadIdx.x;
  if (idx >= F * cols) return;
  int i = idx / cols, c = idx % cols;
  int r = c / D, gf = c % D;
  int h = gf / dh, f = gf % dh;
  const float* w = W + (size_t)i * D + h * dh;
  const float* t = T + ((size_t)(r * HH + h) * dh) * dh + f;
  float s = 0.f;
  for (int d = 0; d < dh; ++d) s = fmaf(w[d], t[(size_t)d * dh], s);
  ushort hh, ll; split2(s, hh, ll);
  Oh[(size_t)c * F + i] = hh;
  Ol[(size_t)c * F + i] = ll;
}

// ---------------- CSR build ----------------
__global__ __launch_bounds__(256) void zero_i32(int* __restrict__ p, int n)
{
  int i = blockIdx.x * 256 + threadIdx.x;
  if (i < n) p[i] = 0;
}

__global__ __launch_bounds__(256) void csr_count(
    const int* __restrict__ EI, int* __restrict__ cnt)
{
  int idx = blockIdx.x * 256 + threadIdx.x;
  if (idx >= ETOT) return;
  int r = idx / EE, e = idx % EE;
  int dst = clampi(EI[(size_t)r * 2 * EE + EE + e], 0, NN - 1);
  atomicAdd(&cnt[dst], 1);
}

__global__ __launch_bounds__(256) void scan_intra(
    int* __restrict__ arr, int* __restrict__ blksum)
{
  __shared__ int s[256];
  const int t = threadIdx.x;
  const int i = blockIdx.x * 256 + t;
  int v = (i < NN) ? arr[i] : 0;
  s[t] = v;
  __syncthreads();
  #pragma unroll
  for (int off = 1; off < 256; off <<= 1) {
    int x = (t >= off) ? s[t - off] : 0;
    __syncthreads();
    s[t] += x;
    __syncthreads();
  }
  if (i < NN) arr[i] = s[t] - v;        // exclusive
  if (t == 255) blksum[blockIdx.x] = s[255];
}

__global__ __launch_bounds__(256) void scan_mid(
    const int* __restrict__ blksum, int* __restrict__ blkoff)
{
  __shared__ int s[256];
  __shared__ int carry;
  const int t = threadIdx.x;
  if (t == 0) carry = 0;
  __syncthreads();
  for (int base = 0; base < NB; base += 256) {
    const int i = base + t;
    int v = (i < NB) ? blksum[i] : 0;
    s[t] = v;
    __syncthreads();
    #pragma unroll
    for (int off = 1; off < 256; off <<= 1) {
      int x = (t >= off) ? s[t - off] : 0;
      __syncthreads();
      s[t] += x;
      __syncthreads();
    }
    if (i < NB) blkoff[i] = carry + s[t] - v;   // global exclusive
    __syncthreads();
    if (t == 255) carry += s[255];
    __syncthreads();
  }
}

__global__ __launch_bounds__(256) void scan_add(
    int* __restrict__ arr, const int* __restrict__ blkoff,
    int* __restrict__ rowptr, int* __restrict__ cursor)
{
  int i = blockIdx.x * 256 + threadIdx.x;
  if (i < NN) {
    int v = arr[i] + blkoff[i >> 8];
    rowptr[i] = v;
    cursor[i] = v;
  }
  if (i == NN) rowptr[NN] = ETOT;
}

__global__ __launch_bounds__(256) void csr_scatter(
    const int* __restrict__ EI, int* __restrict__ cursor,
    int* __restrict__ srcrel)
{
  int idx = blockIdx.x * 256 + threadIdx.x;
  if (idx >= ETOT) return;
  int r = idx / EE, e = idx % EE;
  int src = clampi(EI[(size_t)r * 2 * EE + e], 0, NN - 1);
  int dst = clampi(EI[(size_t)r * 2 * EE + EE + e], 0, NN - 1);
  int pos = atomicAdd(&cursor[dst], 1);
  pos = clampi(pos, 0, ETOT - 1);
  srcrel[pos] = src | (r << 24);
}

// ---------------- fused per-node score+softmax+aggregate (unroll-2) ----------
// kb/vb planar bf16 [N][RR*D]; qin fp32 [N][D]; out split-bf16 agh/agl [N][D].
template<int D, int DH>
__global__ __launch_bounds__(256) void node_fused(
    const ushort* __restrict__ kb, const ushort* __restrict__ vb,
    const float* __restrict__ qin,
    const int* __restrict__ rowptr, const int* __restrict__ srcrel,
    const float* __restrict__ prior,
    ushort* __restrict__ agh, ushort* __restrict__ agl)
{
  constexpr int LPN = D / 2;      // lanes per node (2 feats each)
  constexpr int NPW = 64 / LPN;   // nodes per wave
  constexpr int SUB = DH / 2;     // lanes per head
  const int lane = threadIdx.x & 63;
  const int wv = blockIdx.x * 4 + (threadIdx.x >> 6);
  const int n = wv * NPW + lane / LPN;
  const int sl = lane % LPN;
  if (n >= NN) return;
  const int h = sl / SUB;
  constexpr float scale = (DH == 32) ? 0.17677669529663687f : 0.25f;
  float pr[RR];
  #pragma unroll
  for (int r = 0; r < RR; ++r) pr[r] = prior[r * HH + h] * scale;
  const float2 qq = *(const float2*)&qin[(size_t)n * D + sl * 2];
  const int j0 = clampi(rowptr[n], 0, ETOT);
  const int j1 = clampi(rowptr[n + 1], j0, ETOT);
  float2 acc = make_float2(0.f, 0.f);
  float den = 0.f;
  int j = j0;
  for (; j + 1 < j1; j += 2) {
    const int w0 = srcrel[j];
    const int w1 = srcrel[j + 1];
    const int s0i = clampi(w0 & 0xFFFFFF, 0, NN - 1);
    const int r0  = clampi(w0 >> 24, 0, RR - 1);
    const int s1i = clampi(w1 & 0xFFFFFF, 0, NN - 1);
    const int r1  = clampi(w1 >> 24, 0, RR - 1);
    const size_t b0 = (size_t)s0i * (RR * D) + r0 * D + sl * 2;
    const size_t b1 = (size_t)s1i * (RR * D) + r1 * D + sl * 2;
    const uint ku0 = *(const uint*)&kb[b0];
    const uint vu0 = *(const uint*)&vb[b0];
    const uint ku1 = *(const uint*)&kb[b1];
    const uint vu1 = *(const uint*)&vb[b1];
    float s0 = __uint_as_float(ku0 << 16) * qq.x + __uint_as_float(ku0 & 0xFFFF0000u) * qq.y;
    float s1 = __uint_as_float(ku1 << 16) * qq.x + __uint_as_float(ku1 & 0xFFFF0000u) * qq.y;
    #pragma unroll
    for (int off = SUB / 2; off >= 1; off >>= 1) {
      s0 += __shfl_xor(s0, off, 64);
      s1 += __shfl_xor(s1, off, 64);
    }
    const float ex0 = __expf(s0 * pr[r0]);
    const float ex1 = __expf(s1 * pr[r1]);
    den += ex0 + ex1;
    acc.x = fmaf(ex0, __uint_as_float(vu0 << 16), acc.x);
    acc.y = fmaf(ex0, __uint_as_float(vu0 & 0xFFFF0000u), acc.y);
    acc.x = fmaf(ex1, __uint_as_float(vu1 << 16), acc.x);
    acc.y = fmaf(ex1, __uint_as_float(vu1 & 0xFFFF0000u), acc.y);
  }
  if (j < j1) {
    const int w0 = srcrel[j];
    const int s0i = clampi(w0 & 0xFFFFFF, 0, NN - 1);
    const int r0  = clampi(w0 >> 24, 0, RR - 1);
    const size_t b0 = (size_t)s0i * (RR * D) + r0 * D + sl * 2;
    const uint ku0 = *(const uint*)&kb[b0];
    const uint vu0 = *(const uint*)&vb[b0];
    float s0 = __uint_as_float(ku0 << 16) * qq.x + __uint_as_float(ku0 & 0xFFFF0000u) * qq.y;
    #pragma unroll
    for (int off = SUB / 2; off >= 1; off >>= 1) s0 += __shfl_xor(s0, off, 64);
    const float ex0 = __expf(s0 * pr[r0]);
    den += ex0;
    acc.x = fmaf(ex0, __uint_as_float(vu0 << 16), acc.x);
    acc.y = fmaf(ex0, __uint_as_float(vu0 & 0xFFFF0000u), acc.y);
  }
  const float inv = 1.f / (den + 1e-9f);
  const float ox = acc.x * inv, oy = acc.y * inv;
  ushort h0, l0, h1, l1;
  split2(ox, h0, l0); split2(oy, h1, l1);
  *(uint*)&agh[(size_t)n * D + sl * 2] = (uint)h0 | ((uint)h1 << 16);
  *(uint*)&agl[(size_t)n * D + sl * 2] = (uint)l0 | ((uint)l1 << 16);
}

extern "C" void kernel_launch(void* const* d_in, const int* in_sizes, int n_in,
                              void* d_out, int out_size, void* d_ws, size_t ws_size,
                              hipStream_t stream)
{
  const float* x   = (const float*)d_in[0];
  const int*   EI  = (const int*)  d_in[1];
  const float* Wk1 = (const float*)d_in[2];
  const float* Wq1 = (const float*)d_in[3];
  const float* Wv1 = (const float*)d_in[4];
  const float* A1  = (const float*)d_in[5];
  const float* M1  = (const float*)d_in[6];
  const float* P1  = (const float*)d_in[7];
  const float* Wo1 = (const float*)d_in[8];
  const float* Wk2 = (const float*)d_in[9];
  const float* Wq2 = (const float*)d_in[10];
  const float* Wv2 = (const float*)d_in[11];
  const float* A2  = (const float*)d_in[12];
  const float* M2  = (const float*)d_in[13];
  const float* P2  = (const float*)d_in[14];
  const float* Wo2 = (const float*)d_in[15];
  float* out = (float*)d_out;

  float* ws = (float*)d_ws;
  const size_t nd = (size_t)NN * 128;
  // region X [0, nd): xh|xl -> agh|agl -> q2(fp32, nd/2)|ag2h|ag2l
  ushort* xh  = (ushort*)ws;                 // N*128 bf16
  ushort* xl  = (ushort*)(ws + nd / 2);
  ushort* agh = xh;                          // after L1 GEMMs (x dead)
  ushort* agl = xl;
  float*  q2  = ws;                          // N*64 fp32 (after Wo1: ag dead)
  ushort* ag2h = (ushort*)(ws + nd / 2);     // N*64 bf16
  ushort* ag2l = (ushort*)(ws + nd / 2 + nd / 4);
  // region KV [nd, 4nd): kb [N][384] bf16, vb [N][384] (L2 reuses with 192)
  ushort* kb = (ushort*)(ws + nd);
  ushort* vb = (ushort*)(ws + 5 * nd / 2);
  // region Q [4nd, 5nd): q fp32 -> Hbh|Hbl after node_fused L1
  float*  q   = ws + 4 * nd;                 // N*128 fp32
  ushort* Hbh = (ushort*)(ws + 4 * nd);
  ushort* Hbl = (ushort*)(ws + 4 * nd + nd / 2);
  // tail: concat weights + CSR ints (same as proven round-11 layout)
  ushort* WBth = (ushort*)(ws + 5 * nd);     // up to 896*128
  ushort* WBtl = WBth + 896 * 128;
  int* ints   = (int*)(WBtl + 896 * 128);
  int* rowptr = ints;              // NN+1
  int* cursor = rowptr + NN + 1;   // NN
  int* blks   = cursor + NN;       // 2*NB
  int* srcrel = blks + 2 * NB;     // ETOT (src | r<<24, dst-sorted)

  const size_t need_bytes = (5 * nd + 114688) * 4 +
      ((size_t)(NN + 1) + NN + 2 * NB + ETOT) * 4;
  if (ws_size < need_bytes) return;   // visible absmax failure, not a fault

  dim3 blk(256);
  const int GB = (NN + 127) / 128;    // 782 row-blocks

  // ---------- prep: split x, build L1 weights ----------
  split_a<<<dim3((NN * 128 / 8 + 255) / 256), blk, 0, stream>>>(x, xh, xl, NN * 128 / 8);
  build_wT<<<dim3(192), blk, 0, stream>>>(Wk1, A1, WBth, WBtl, 128, 128, 32);
  build_wT<<<dim3(192), blk, 0, stream>>>(Wv1, M1, WBth + 384 * 128, WBtl + 384 * 128, 128, 128, 32);
  convt<<<dim3(64), blk, 0, stream>>>(Wq1, WBth + 768 * 128, WBtl + 768 * 128, 128, 128);

  // ---------- Layer 1 GEMMs ----------
  gemm_bf1<4><<<dim3(GB), blk, 0, stream>>>(xh, WBth, NN, 768, kb, 384, vb);
  gemm_sp3<4><<<dim3(GB), blk, 0, stream>>>(xh, xl, WBth + 768 * 128, WBtl + 768 * 128,
                                            NN, 128, q, (ushort*)nullptr, (ushort*)nullptr, 0);

  // ---------- CSR build (shared by both layers) ----------
  zero_i32<<<dim3(NB), blk, 0, stream>>>(cursor, NN);
  csr_count<<<dim3((ETOT + 255) / 256), blk, 0, stream>>>(EI, cursor);
  scan_intra<<<dim3(NB), blk, 0, stream>>>(cursor, blks);
  scan_mid<<<dim3(1), blk, 0, stream>>>(blks, blks + NB);
  scan_add<<<dim3(NB), blk, 0, stream>>>(cursor, blks + NB, rowptr, cursor);
  csr_scatter<<<dim3((ETOT + 255) / 256), blk, 0, stream>>>(EI, cursor, srcrel);

  // ---------- Layer 1 edge + output ----------
  node_fused<128, 32><<<dim3((NN + 3) / 4), blk, 0, stream>>>(kb, vb, q, rowptr, srcrel, P1, agh, agl);
  convt<<<dim3(64), blk, 0, stream>>>(Wo1, WBth, WBtl, 128, 128);
  gemm_sp3<4><<<dim3(GB), blk, 0, stream>>>(agh, agl, WBth, WBtl,
                                            NN, 128, (float*)nullptr, Hbh, Hbl, 1);  // relu+split

  // ---------- Layer 2 ----------
  build_wT<<<dim3(96), blk, 0, stream>>>(Wk2, A2, WBth, WBtl, 128, 64, 16);
  build_wT<<<dim3(96), blk, 0, stream>>>(Wv2, M2, WBth + 192 * 128, WBtl + 192 * 128, 128, 64, 16);
  convt<<<dim3(32), blk, 0, stream>>>(Wq2, WBth + 384 * 128, WBtl + 384 * 128, 128, 64);
  gemm_bf1<4><<<dim3(GB), blk, 0, stream>>>(Hbh, WBth, NN, 384, kb, 192, vb);
  gemm_sp3<4><<<dim3(GB), blk, 0, stream>>>(Hbh, Hbl, WBth + 384 * 128, WBtl + 384 * 128,
                                            NN, 64, q2, (ushort*)nullptr, (ushort*)nullptr, 0);
  node_fused<64, 16><<<dim3((NN + 7) / 8), blk, 0, stream>>>(kb, vb, q2, rowptr, srcrel, P2, ag2h, ag2l);
  convt<<<dim3(16), blk, 0, stream>>>(Wo2, WBth, WBtl, 64, 64);
  gemm_sp3<2><<<dim3(GB), blk, 0, stream>>>(ag2h, ag2l, WBth, WBtl,
                                            NN, 64, out, (ushort*)nullptr, (ushort*)nullptr, 0);
}

// Round 14
// 350.731 us; speedup vs baseline: 5.2445x; 1.1883x over previous
//
#include <hip/hip_runtime.h>

#define NN 100000
#define RR 3
#define EE 200000
#define HH 4
#define ETOT (RR * EE)
#define NB ((NN + 255) / 256)

typedef __attribute__((ext_vector_type(8))) short bf16x8;
typedef __attribute__((ext_vector_type(4))) float f32x4;

__device__ __forceinline__ int clampi(int v, int lo, int hi) {
  return v < lo ? lo : (v > hi ? hi : v);
}

// split fp32 -> bf16 hi + bf16 lo (RNE both)
__device__ __forceinline__ void split2(float v, ushort& h, ushort& l) {
  uint u = __float_as_uint(v);
  uint hb = (u + 0x7FFFu + ((u >> 16) & 1u)) >> 16;
  float fh = __uint_as_float(hb << 16);
  float r = v - fh;
  uint ur = __float_as_uint(r);
  uint lb = (ur + 0x7FFFu + ((ur >> 16) & 1u)) >> 16;
  h = (ushort)hb; l = (ushort)lb;
}

__device__ __forceinline__ ushort f2bf(float v) {
  uint u = __float_as_uint(v);
  return (ushort)((u + 0x7FFFu + ((u >> 16) & 1u)) >> 16);
}

// ---------------- fp32 -> bf16 (hi only) ----------------
__global__ __launch_bounds__(256) void to_bf16(
    const float* __restrict__ A, ushort* __restrict__ Ah, int total8)
{
  int idx = blockIdx.x * 256 + threadIdx.x;
  if (idx >= total8) return;
  const float4* ap = (const float4*)(A + (size_t)idx * 8);
  float4 a0 = ap[0], a1 = ap[1];
  const float v[8] = {a0.x, a0.y, a0.z, a0.w, a1.x, a1.y, a1.z, a1.w};
  ushort h[8];
  #pragma unroll
  for (int i = 0; i < 8; ++i) h[i] = f2bf(v[i]);
  *(uint4*)(Ah + (size_t)idx * 8) = *(const uint4*)h;
}

// ---------------- pure-bf16 persistent-A GEMM (1 MFMA/tile) ----------------
// A bf16 [M][K]; B bf16 [NTOT][K]. Routing: cols [0,nk)->kb, [nk,2nk)->vb
// (stride nk), rest -> qb (stride nq, optional relu). All outputs planar bf16.
template<int KT>   // K = KT*32
__global__ __launch_bounds__(256) void gemm_bf1(
    const ushort* __restrict__ Ah, const ushort* __restrict__ Bth,
    int M, int NTOT,
    ushort* __restrict__ kb, int nk, ushort* __restrict__ vb,
    ushort* __restrict__ qb, int nq, int reluq)
{
  constexpr int K = KT * 32;
  constexpr int LDB = KT * 16 + 4;
  __shared__ uint Bs[2][64 * LDB];
  const int tid = threadIdx.x;
  const int m0 = blockIdx.x * 128;
  const int lane = tid & 63, wv = tid >> 6;
  const int rbase = m0 + wv * 32 + (lane & 15);
  const int kof = (lane >> 4) * 8;

  bf16x8 a[2][KT];
  #pragma unroll
  for (int m = 0; m < 2; ++m) {
    const int row = rbase + m * 16;
    #pragma unroll
    for (int kt = 0; kt < KT; ++kt) {
      uint4 u = make_uint4(0, 0, 0, 0);
      if (row < M) u = *(const uint4*)(Ah + (size_t)row * K + kt * 32 + kof);
      a[m][kt] = *reinterpret_cast<bf16x8*>(&u);
    }
  }

  auto stage = [&](int cb, int b) {
    const int c = tid >> 2, kq = tid & 3;
    if (kq * 32 < K) {
      const uint4* s = (const uint4*)(Bth + (size_t)(cb + c) * K + kq * 32);
      uint4* d = (uint4*)&Bs[b][c * LDB + kq * 16];
      #pragma unroll
      for (int q = 0; q < 4; ++q) d[q] = s[q];
    }
  };
  stage(0, 0);
  __syncthreads();
  int buf = 0;

  for (int cb = 0; cb < NTOT; cb += 64) {
    if (cb + 64 < NTOT) stage(cb + 64, buf ^ 1);

    f32x4 acc[2][4];
    #pragma unroll
    for (int m = 0; m < 2; ++m)
      #pragma unroll
      for (int n = 0; n < 4; ++n) acc[m][n] = (f32x4){0.f, 0.f, 0.f, 0.f};

    #pragma unroll
    for (int kt = 0; kt < KT; ++kt) {
      #pragma unroll
      for (int n = 0; n < 4; ++n) {
        const int boff = (n * 16 + (lane & 15)) * LDB + kt * 16 + (lane >> 4) * 4;
        uint4 u = *(const uint4*)&Bs[buf][boff];
        bf16x8 b8 = *reinterpret_cast<bf16x8*>(&u);
        acc[0][n] = __builtin_amdgcn_mfma_f32_16x16x32_bf16(a[0][kt], b8, acc[0][n], 0, 0, 0);
        acc[1][n] = __builtin_amdgcn_mfma_f32_16x16x32_bf16(a[1][kt], b8, acc[1][n], 0, 0, 0);
      }
    }

    // routing (chunk-uniform); C/D frag: col=lane&15, row=(lane>>4)*4+j
    ushort* ob; int stride, cbase, relu = 0;
    if (cb < nk)            { ob = kb; stride = nk; cbase = cb; }
    else if (cb < 2 * nk)   { ob = vb; stride = nk; cbase = cb - nk; }
    else                    { ob = qb; stride = nq; cbase = cb - 2 * nk; relu = reluq; }
    #pragma unroll
    for (int m = 0; m < 2; ++m) {
      const int rw = m0 + wv * 32 + m * 16 + (lane >> 4) * 4;
      #pragma unroll
      for (int n = 0; n < 4; ++n) {
        const int col = cbase + n * 16 + (lane & 15);
        #pragma unroll
        for (int j = 0; j < 4; ++j) {
          if (rw + j < M) {
            float o = acc[m][n][j];
            if (relu) o = fmaxf(o, 0.f);
            ob[(size_t)(rw + j) * stride + col] = f2bf(o);
          }
        }
      }
    }
    __syncthreads();
    buf ^= 1;
  }
}

// ---------------- split-bf16 persistent-A GEMM (3 MFMA/tile), fp32 out -------
// Used only for the final Wo2 GEMM (direct output accuracy).
template<int KT>
__global__ __launch_bounds__(256) void gemm_sp3(
    const ushort* __restrict__ Ah, const ushort* __restrict__ Al,
    const ushort* __restrict__ Bth, const ushort* __restrict__ Btl,
    int M, int NTOT, float* __restrict__ of)
{
  constexpr int K = KT * 32;
  constexpr int LDB = KT * 16 + 4;
  __shared__ uint Bh[64 * LDB];
  __shared__ uint Bl[64 * LDB];
  const int tid = threadIdx.x;
  const int m0 = blockIdx.x * 128;
  const int lane = tid & 63, wv = tid >> 6;
  const int rbase = m0 + wv * 32 + (lane & 15);
  const int kof = (lane >> 4) * 8;

  bf16x8 ah[2][KT], al[2][KT];
  #pragma unroll
  for (int m = 0; m < 2; ++m) {
    const int row = rbase + m * 16;
    #pragma unroll
    for (int kt = 0; kt < KT; ++kt) {
      uint4 uh = make_uint4(0, 0, 0, 0), ul = make_uint4(0, 0, 0, 0);
      if (row < M) {
        uh = *(const uint4*)(Ah + (size_t)row * K + kt * 32 + kof);
        ul = *(const uint4*)(Al + (size_t)row * K + kt * 32 + kof);
      }
      ah[m][kt] = *reinterpret_cast<bf16x8*>(&uh);
      al[m][kt] = *reinterpret_cast<bf16x8*>(&ul);
    }
  }

  for (int cb = 0; cb < NTOT; cb += 64) {
    {
      const int c = tid >> 2, kq = tid & 3;
      if (kq * 32 < K) {
        const uint4* sh = (const uint4*)(Bth + (size_t)(cb + c) * K + kq * 32);
        const uint4* sl = (const uint4*)(Btl + (size_t)(cb + c) * K + kq * 32);
        uint4* dh = (uint4*)&Bh[c * LDB + kq * 16];
        uint4* dl = (uint4*)&Bl[c * LDB + kq * 16];
        #pragma unroll
        for (int q = 0; q < 4; ++q) { dh[q] = sh[q]; dl[q] = sl[q]; }
      }
    }
    __syncthreads();

    f32x4 acc[2][4];
    #pragma unroll
    for (int m = 0; m < 2; ++m)
      #pragma unroll
      for (int n = 0; n < 4; ++n) acc[m][n] = (f32x4){0.f, 0.f, 0.f, 0.f};

    #pragma unroll
    for (int kt = 0; kt < KT; ++kt) {
      #pragma unroll
      for (int n = 0; n < 4; ++n) {
        const int boff = (n * 16 + (lane & 15)) * LDB + kt * 16 + (lane >> 4) * 4;
        uint4 uh = *(const uint4*)&Bh[boff];
        uint4 ul = *(const uint4*)&Bl[boff];
        bf16x8 bh = *reinterpret_cast<bf16x8*>(&uh);
        bf16x8 bl = *reinterpret_cast<bf16x8*>(&ul);
        #pragma unroll
        for (int m = 0; m < 2; ++m) {
          acc[m][n] = __builtin_amdgcn_mfma_f32_16x16x32_bf16(ah[m][kt], bh, acc[m][n], 0, 0, 0);
          acc[m][n] = __builtin_amdgcn_mfma_f32_16x16x32_bf16(ah[m][kt], bl, acc[m][n], 0, 0, 0);
          acc[m][n] = __builtin_amdgcn_mfma_f32_16x16x32_bf16(al[m][kt], bh, acc[m][n], 0, 0, 0);
        }
      }
    }

    #pragma unroll
    for (int m = 0; m < 2; ++m) {
      const int rw = m0 + wv * 32 + m * 16 + (lane >> 4) * 4;
      #pragma unroll
      for (int n = 0; n < 4; ++n) {
        const int col = cb + n * 16 + (lane & 15);
        #pragma unroll
        for (int j = 0; j < 4; ++j)
          if (rw + j < M) of[(size_t)(rw + j) * NTOT + col] = acc[m][n][j];
      }
    }
    __syncthreads();
  }
}

// ---------------- plain weight -> transposed split-bf16 ----------------
__global__ __launch_bounds__(256) void convt(
    const float* __restrict__ W, ushort* __restrict__ Th, ushort* __restrict__ Tl,
    int K, int N)
{
  int idx = blockIdx.x * 256 + threadIdx.x;
  if (idx >= K * N) return;
  int n = idx / K, k = idx % K;
  ushort h, l; split2(W[(size_t)k * N + n], h, l);
  Th[(size_t)n * K + k] = h;
  Tl[(size_t)n * K + k] = l;
}

// ---------------- weight-space fusion -> transposed split-bf16 ----------------
__global__ __launch_bounds__(256) void build_wT(
    const float* __restrict__ W, const float* __restrict__ T,
    ushort* __restrict__ Oh, ushort* __restrict__ Ol, int F, int D, int dh)
{
  const int cols = RR * D;
  int idx = blockIdx.x * 256 + threadIdx.x;
  if (idx >= F * cols) return;
  int i = idx / cols, c = idx % cols;
  int r = c / D, gf = c % D;
  int h = gf / dh, f = gf % dh;
  const float* w = W + (size_t)i * D + h * dh;
  const float* t = T + ((size_t)(r * HH + h) * dh) * dh + f;
  float s = 0.f;
  for (int d = 0; d < dh; ++d) s = fmaf(w[d], t[(size_t)d * dh], s);
  ushort hh, ll; split2(s, hh, ll);
  Oh[(size_t)c * F + i] = hh;
  Ol[(size_t)c * F + i] = ll;
}

// ---------------- CSR build ----------------
__global__ __launch_bounds__(256) void zero_i32(int* __restrict__ p, int n)
{
  int i = blockIdx.x * 256 + threadIdx.x;
  if (i < n) p[i] = 0;
}

__global__ __launch_bounds__(256) void csr_count(
    const int* __restrict__ EI, int* __restrict__ cnt)
{
  int idx = blockIdx.x * 256 + threadIdx.x;
  if (idx >= ETOT) return;
  int r = idx / EE, e = idx % EE;
  int dst = clampi(EI[(size_t)r * 2 * EE + EE + e], 0, NN - 1);
  atomicAdd(&cnt[dst], 1);
}

__global__ __launch_bounds__(256) void scan_intra(
    int* __restrict__ arr, int* __restrict__ blksum)
{
  __shared__ int s[256];
  const int t = threadIdx.x;
  const int i = blockIdx.x * 256 + t;
  int v = (i < NN) ? arr[i] : 0;
  s[t] = v;
  __syncthreads();
  #pragma unroll
  for (int off = 1; off < 256; off <<= 1) {
    int x = (t >= off) ? s[t - off] : 0;
    __syncthreads();
    s[t] += x;
    __syncthreads();
  }
  if (i < NN) arr[i] = s[t] - v;        // exclusive
  if (t == 255) blksum[blockIdx.x] = s[255];
}

__global__ __launch_bounds__(256) void scan_mid(
    const int* __restrict__ blksum, int* __restrict__ blkoff)
{
  __shared__ int s[256];
  __shared__ int carry;
  const int t = threadIdx.x;
  if (t == 0) carry = 0;
  __syncthreads();
  for (int base = 0; base < NB; base += 256) {
    const int i = base + t;
    int v = (i < NB) ? blksum[i] : 0;
    s[t] = v;
    __syncthreads();
    #pragma unroll
    for (int off = 1; off < 256; off <<= 1) {
      int x = (t >= off) ? s[t - off] : 0;
      __syncthreads();
      s[t] += x;
      __syncthreads();
    }
    if (i < NB) blkoff[i] = carry + s[t] - v;   // global exclusive
    __syncthreads();
    if (t == 255) carry += s[255];
    __syncthreads();
  }
}

__global__ __launch_bounds__(256) void scan_add(
    int* __restrict__ arr, const int* __restrict__ blkoff,
    int* __restrict__ rowptr, int* __restrict__ cursor)
{
  int i = blockIdx.x * 256 + threadIdx.x;
  if (i < NN) {
    int v = arr[i] + blkoff[i >> 8];
    rowptr[i] = v;
    cursor[i] = v;
  }
  if (i == NN) rowptr[NN] = ETOT;
}

__global__ __launch_bounds__(256) void csr_scatter(
    const int* __restrict__ EI, int* __restrict__ cursor,
    int* __restrict__ srcrel)
{
  int idx = blockIdx.x * 256 + threadIdx.x;
  if (idx >= ETOT) return;
  int r = idx / EE, e = idx % EE;
  int src = clampi(EI[(size_t)r * 2 * EE + e], 0, NN - 1);
  int dst = clampi(EI[(size_t)r * 2 * EE + EE + e], 0, NN - 1);
  int pos = atomicAdd(&cursor[dst], 1);
  pos = clampi(pos, 0, ETOT - 1);
  srcrel[pos] = src | (r << 24);
}

// ---------------- fused per-node score+softmax+aggregate (unroll-2) ----------
// kb/vb planar bf16 [N][RR*D]; qb planar bf16 [N][D]; out agh (+agl if !=null).
// Clamps on all srcrel-derived indices: load-bearing (rounds 5->6 and 12->13
// proved crash<->pass flips on exactly this) — do not remove.
template<int D, int DH>
__global__ __launch_bounds__(256) void node_fused(
    const ushort* __restrict__ kb, const ushort* __restrict__ vb,
    const ushort* __restrict__ qb,
    const int* __restrict__ rowptr, const int* __restrict__ srcrel,
    const float* __restrict__ prior,
    ushort* __restrict__ agh, ushort* __restrict__ agl)
{
  constexpr int LPN = D / 2;      // lanes per node (2 feats each)
  constexpr int NPW = 64 / LPN;   // nodes per wave
  constexpr int SUB = DH / 2;     // lanes per head
  const int lane = threadIdx.x & 63;
  const int wv = blockIdx.x * 4 + (threadIdx.x >> 6);
  const int n = wv * NPW + lane / LPN;
  const int sl = lane % LPN;
  if (n >= NN) return;
  const int h = sl / SUB;
  constexpr float scale = (DH == 32) ? 0.17677669529663687f : 0.25f;
  float pr[RR];
  #pragma unroll
  for (int r = 0; r < RR; ++r) pr[r] = prior[r * HH + h] * scale;
  const uint qu = *(const uint*)&qb[(size_t)n * D + sl * 2];
  const float qx = __uint_as_float(qu << 16);
  const float qy = __uint_as_float(qu & 0xFFFF0000u);
  const int j0 = clampi(rowptr[n], 0, ETOT);
  const int j1 = clampi(rowptr[n + 1], j0, ETOT);
  float2 acc = make_float2(0.f, 0.f);
  float den = 0.f;
  int j = j0;
  for (; j + 1 < j1; j += 2) {
    const int w0 = srcrel[j];
    const int w1 = srcrel[j + 1];
    const int s0i = clampi(w0 & 0xFFFFFF, 0, NN - 1);
    const int r0  = clampi(w0 >> 24, 0, RR - 1);
    const int s1i = clampi(w1 & 0xFFFFFF, 0, NN - 1);
    const int r1  = clampi(w1 >> 24, 0, RR - 1);
    const size_t b0 = (size_t)s0i * (RR * D) + r0 * D + sl * 2;
    const size_t b1 = (size_t)s1i * (RR * D) + r1 * D + sl * 2;
    const uint ku0 = *(const uint*)&kb[b0];
    const uint vu0 = *(const uint*)&vb[b0];
    const uint ku1 = *(const uint*)&kb[b1];
    const uint vu1 = *(const uint*)&vb[b1];
    float s0 = __uint_as_float(ku0 << 16) * qx + __uint_as_float(ku0 & 0xFFFF0000u) * qy;
    float s1 = __uint_as_float(ku1 << 16) * qx + __uint_as_float(ku1 & 0xFFFF0000u) * qy;
    #pragma unroll
    for (int off = SUB / 2; off >= 1; off >>= 1) {
      s0 += __shfl_xor(s0, off, 64);
      s1 += __shfl_xor(s1, off, 64);
    }
    const float ex0 = __expf(s0 * pr[r0]);
    const float ex1 = __expf(s1 * pr[r1]);
    den += ex0 + ex1;
    acc.x = fmaf(ex0, __uint_as_float(vu0 << 16), acc.x);
    acc.y = fmaf(ex0, __uint_as_float(vu0 & 0xFFFF0000u), acc.y);
    acc.x = fmaf(ex1, __uint_as_float(vu1 << 16), acc.x);
    acc.y = fmaf(ex1, __uint_as_float(vu1 & 0xFFFF0000u), acc.y);
  }
  if (j < j1) {
    const int w0 = srcrel[j];
    const int s0i = clampi(w0 & 0xFFFFFF, 0, NN - 1);
    const int r0  = clampi(w0 >> 24, 0, RR - 1);
    const size_t b0 = (size_t)s0i * (RR * D) + r0 * D + sl * 2;
    const uint ku0 = *(const uint*)&kb[b0];
    const uint vu0 = *(const uint*)&vb[b0];
    float s0 = __uint_as_float(ku0 << 16) * qx + __uint_as_float(ku0 & 0xFFFF0000u) * qy;
    #pragma unroll
    for (int off = SUB / 2; off >= 1; off >>= 1) s0 += __shfl_xor(s0, off, 64);
    const float ex0 = __expf(s0 * pr[r0]);
    den += ex0;
    acc.x = fmaf(ex0, __uint_as_float(vu0 << 16), acc.x);
    acc.y = fmaf(ex0, __uint_as_float(vu0 & 0xFFFF0000u), acc.y);
  }
  const float inv = 1.f / (den + 1e-9f);
  const float ox = acc.x * inv, oy = acc.y * inv;
  if (agl) {
    ushort h0, l0, h1, l1;
    split2(ox, h0, l0); split2(oy, h1, l1);
    *(uint*)&agh[(size_t)n * D + sl * 2] = (uint)h0 | ((uint)h1 << 16);
    *(uint*)&agl[(size_t)n * D + sl * 2] = (uint)l0 | ((uint)l1 << 16);
  } else {
    *(uint*)&agh[(size_t)n * D + sl * 2] = (uint)f2bf(ox) | ((uint)f2bf(oy) << 16);
  }
}

extern "C" void kernel_launch(void* const* d_in, const int* in_sizes, int n_in,
                              void* d_out, int out_size, void* d_ws, size_t ws_size,
                              hipStream_t stream)
{
  const float* x   = (const float*)d_in[0];
  const int*   EI  = (const int*)  d_in[1];
  const float* Wk1 = (const float*)d_in[2];
  const float* Wq1 = (const float*)d_in[3];
  const float* Wv1 = (const float*)d_in[4];
  const float* A1  = (const float*)d_in[5];
  const float* M1  = (const float*)d_in[6];
  const float* P1  = (const float*)d_in[7];
  const float* Wo1 = (const float*)d_in[8];
  const float* Wk2 = (const float*)d_in[9];
  const float* Wq2 = (const float*)d_in[10];
  const float* Wv2 = (const float*)d_in[11];
  const float* A2  = (const float*)d_in[12];
  const float* M2  = (const float*)d_in[13];
  const float* P2  = (const float*)d_in[14];
  const float* Wo2 = (const float*)d_in[15];
  float* out = (float*)d_out;

  float* ws = (float*)d_ws;
  const size_t nd = (size_t)NN * 128;
  // ---- float-offset layout (all sizes in floats; all 16B-aligned) ----
  // [0, nd/2):    xh (N*128 bf16 = nd/2) -> agh (same size) -> then:
  //               qb2 [0,nd/4) + ag2h [nd/4,nd/2)   (both N*64 bf16 = nd/4)
  // [nd/2, nd):   qb1 (N*128 bf16) -> ag2l [nd/2, 3nd/4)
  // [nd, 5nd/2):  kb  (N*384 bf16 = 3nd/2)
  // [5nd/2, 4nd): vb
  // [4nd, 4.5nd): Hbh (N*128 bf16)
  // [5nd, ...):   WBth|WBtl (896*128 each) + CSR ints
  ushort* xh   = (ushort*)ws;
  ushort* agh  = xh;
  ushort* qb2  = (ushort*)ws;                      // [0, nd/4)
  ushort* ag2h = (ushort*)(ws + nd / 4);           // [nd/4, nd/2)
  ushort* qb1  = (ushort*)(ws + nd / 2);           // [nd/2, nd)
  ushort* ag2l = (ushort*)(ws + nd / 2);           // [nd/2, 3nd/4) (qb1 dead)
  ushort* kb   = (ushort*)(ws + nd);
  ushort* vb   = (ushort*)(ws + 5 * nd / 2);
  ushort* Hbh  = (ushort*)(ws + 4 * nd);
  ushort* WBth = (ushort*)(ws + 5 * nd);
  ushort* WBtl = WBth + 896 * 128;
  int* ints   = (int*)(WBtl + 896 * 128);
  int* rowptr = ints;              // NN+1
  int* cursor = rowptr + NN + 1;   // NN
  int* blks   = cursor + NN;       // 2*NB
  int* srcrel = blks + 2 * NB;     // ETOT (src | r<<24, dst-sorted)

  const size_t need_bytes = (5 * nd + 114688) * 4 +
      ((size_t)(NN + 1) + NN + 2 * NB + ETOT) * 4;
  if (ws_size < need_bytes) return;   // visible absmax failure, not a fault

  dim3 blk(256);
  const int GB = (NN + 127) / 128;    // 782 row-blocks

  // ---------- prep: x -> bf16, L1 concat weights ----------
  to_bf16<<<dim3((NN * 128 / 8 + 255) / 256), blk, 0, stream>>>(x, xh, NN * 128 / 8);
  build_wT<<<dim3(192), blk, 0, stream>>>(Wk1, A1, WBth, WBtl, 128, 128, 32);
  build_wT<<<dim3(192), blk, 0, stream>>>(Wv1, M1, WBth + 384 * 128, WBtl + 384 * 128, 128, 128, 32);
  convt<<<dim3(64), blk, 0, stream>>>(Wq1, WBth + 768 * 128, WBtl + 768 * 128, 128, 128);

  // ---------- Layer 1: ONE bf16 GEMM for kA|vM|q ----------
  gemm_bf1<4><<<dim3(GB), blk, 0, stream>>>(xh, WBth, NN, 896, kb, 384, vb, qb1, 128, 0);

  // ---------- CSR build (shared by both layers) ----------
  zero_i32<<<dim3(NB), blk, 0, stream>>>(cursor, NN);
  csr_count<<<dim3((ETOT + 255) / 256), blk, 0, stream>>>(EI, cursor);
  scan_intra<<<dim3(NB), blk, 0, stream>>>(cursor, blks);
  scan_mid<<<dim3(1), blk, 0, stream>>>(blks, blks + NB);
  scan_add<<<dim3(NB), blk, 0, stream>>>(cursor, blks + NB, rowptr, cursor);
  csr_scatter<<<dim3((ETOT + 255) / 256), blk, 0, stream>>>(EI, cursor, srcrel);

  // ---------- Layer 1 edge + output (agh overwrites dead xh) ----------
  node_fused<128, 32><<<dim3((NN + 3) / 4), blk, 0, stream>>>(
      kb, vb, qb1, rowptr, srcrel, P1, agh, (ushort*)nullptr);
  convt<<<dim3(64), blk, 0, stream>>>(Wo1, WBth, WBtl, 128, 128);
  gemm_bf1<4><<<dim3(GB), blk, 0, stream>>>(agh, WBth, NN, 128,
                                            (ushort*)nullptr, 0, (ushort*)nullptr,
                                            Hbh, 128, 1);   // relu

  // ---------- Layer 2: ONE bf16 GEMM for kA2|vM2|q2 ----------
  // qb2 overwrites agh (dead after Wo1 GEMM above).
  build_wT<<<dim3(96), blk, 0, stream>>>(Wk2, A2, WBth, WBtl, 128, 64, 16);
  build_wT<<<dim3(96), blk, 0, stream>>>(Wv2, M2, WBth + 192 * 128, WBtl + 192 * 128, 128, 64, 16);
  convt<<<dim3(32), blk, 0, stream>>>(Wq2, WBth + 384 * 128, WBtl + 384 * 128, 128, 64);
  gemm_bf1<4><<<dim3(GB), blk, 0, stream>>>(Hbh, WBth, NN, 448, kb, 192, vb, qb2, 64, 0);

  // ag2h -> [nd/4,nd/2) (dead agh upper half); ag2l -> [nd/2,3nd/4) (dead qb1)
  node_fused<64, 16><<<dim3((NN + 7) / 8), blk, 0, stream>>>(
      kb, vb, qb2, rowptr, srcrel, P2, ag2h, ag2l);
  convt<<<dim3(16), blk, 0, stream>>>(Wo2, WBth, WBtl, 64, 64);
  gemm_sp3<2><<<dim3(GB), blk, 0, stream>>>(ag2h, ag2l, WBth, WBtl, NN, 64, out);
}